// Round 2
// baseline (2505.691 us; speedup 1.0000x reference)
//
#include <hip/hip_runtime.h>
#include <math.h>

// ---------------------------------------------------------------------------
// QuantizedAttention (round 1): fp32 vector implementation, 128x128 GEMM tiles.
//   k1: qkv = x @ w_qkv^T            (tiled fp32 GEMM, 128x128 tile, 8x8/thread)
//   k2: fake-quant q,k per (b,n,h) row of 72 (in place in qkv buffer)
//   k3: fake-quant v per (b,h,d) column of 2048 (in place)
//   k4: fused attention: two-pass flash (pass A row-max, pass B exp/round/PV)
//       exploiting: attn_q = rint(255*exp(l-lmax)) * (1/(255*Z)); Z applied at end.
//   k5: out = attn_out @ w_proj^T + b_proj
// Workspace: qkv (56.6 MB) + attn_out (18.9 MB) = 75.5 MB.
// jnp.round == round-half-even -> rintf everywhere.
// ---------------------------------------------------------------------------

constexpr int Bz   = 2;
constexpr int Ntok = 2048;
constexpr int DIMC = 1152;
constexpr int H    = 16;
constexpr int HD_  = 72;
constexpr int Mrows = Bz * Ntok;   // 4096
constexpr int C3    = 3 * DIMC;    // 3456

// ---------------- GEMM: C[m][n] = sum_k A[m][k] * W[n][k] (+ bias[n]) -------
// 128x128 tile, BK=16, 256 threads, 8x8 acc/thread.
template<bool BIAS>
__global__ __launch_bounds__(256)
void gemm_bt(const float* __restrict__ A, const float* __restrict__ W,
             const float* __restrict__ bias, float* __restrict__ Cout,
             int Md, int Nd, int Kd) {
  __shared__ float As[16][132];   // [k][m], 132-float stride (16B aligned, pad 4)
  __shared__ float Bs[16][132];   // [k][n]
  const int t  = threadIdx.x;
  const int bm = blockIdx.y << 7, bn = blockIdx.x << 7;
  const int lr = t >> 1;             // 0..127: tile row loaded by this thread
  const int lk = (t & 1) << 3;       // 0 or 8: k-offset
  const float* Ap = A + (size_t)(bm + lr) * Kd + lk;
  const float* Wp = W + (size_t)(bn + lr) * Kd + lk;
  const int tx = t & 15, ty = t >> 4;   // 16x16 thread grid, 8x8 each
  float acc[8][8] = {};
  for (int k0 = 0; k0 < Kd; k0 += 16) {
    float4 a0 = *(const float4*)(Ap + k0);
    float4 a1 = *(const float4*)(Ap + k0 + 4);
    float4 w0 = *(const float4*)(Wp + k0);
    float4 w1 = *(const float4*)(Wp + k0 + 4);
    __syncthreads();               // previous iteration's compute done
    As[lk + 0][lr] = a0.x; As[lk + 1][lr] = a0.y;
    As[lk + 2][lr] = a0.z; As[lk + 3][lr] = a0.w;
    As[lk + 4][lr] = a1.x; As[lk + 5][lr] = a1.y;
    As[lk + 6][lr] = a1.z; As[lk + 7][lr] = a1.w;
    Bs[lk + 0][lr] = w0.x; Bs[lk + 1][lr] = w0.y;
    Bs[lk + 2][lr] = w0.z; Bs[lk + 3][lr] = w0.w;
    Bs[lk + 4][lr] = w1.x; Bs[lk + 5][lr] = w1.y;
    Bs[lk + 6][lr] = w1.z; Bs[lk + 7][lr] = w1.w;
    __syncthreads();
#pragma unroll
    for (int kk = 0; kk < 16; ++kk) {
      float4 x0 = *(const float4*)&As[kk][(ty << 3) + 0];
      float4 x1 = *(const float4*)&As[kk][(ty << 3) + 4];
      float4 y0 = *(const float4*)&Bs[kk][(tx << 3) + 0];
      float4 y1 = *(const float4*)&Bs[kk][(tx << 3) + 4];
      float ar[8] = {x0.x, x0.y, x0.z, x0.w, x1.x, x1.y, x1.z, x1.w};
      float br[8] = {y0.x, y0.y, y0.z, y0.w, y1.x, y1.y, y1.z, y1.w};
#pragma unroll
      for (int i = 0; i < 8; ++i)
#pragma unroll
        for (int j = 0; j < 8; ++j)
          acc[i][j] = fmaf(ar[i], br[j], acc[i][j]);
    }
  }
  float bias8[8] = {0.f, 0.f, 0.f, 0.f, 0.f, 0.f, 0.f, 0.f};
  if (BIAS) {
#pragma unroll
    for (int j = 0; j < 8; ++j) bias8[j] = bias[bn + (tx << 3) + j];
  }
#pragma unroll
  for (int i = 0; i < 8; ++i) {
    const int m = bm + (ty << 3) + i;
    float* cp = Cout + (size_t)m * Nd + bn + (tx << 3);
    float4 o0, o1;
    o0.x = acc[i][0] + bias8[0]; o0.y = acc[i][1] + bias8[1];
    o0.z = acc[i][2] + bias8[2]; o0.w = acc[i][3] + bias8[3];
    o1.x = acc[i][4] + bias8[4]; o1.y = acc[i][5] + bias8[5];
    o1.z = acc[i][6] + bias8[6]; o1.w = acc[i][7] + bias8[7];
    *(float4*)(cp + 0) = o0;
    *(float4*)(cp + 4) = o1;
  }
}

// --------- fake-quant q,k: per (b,n,{q,k},h) row of 72, symmetric int8 -----
__global__ __launch_bounds__(256)
void quant_qk(float* __restrict__ qkv) {
  const int wid  = (blockIdx.x << 2) + (threadIdx.x >> 6);  // one wave per row
  const int lane = threadIdx.x & 63;
  const int h  = wid & 15;
  const int g  = (wid >> 4) & 1;        // 0=q, 1=k
  const int bn = wid >> 5;              // 0..4095
  float* row = qkv + (size_t)bn * C3 + g * DIMC + h * HD_;
  float x0 = row[lane];
  float x1 = (lane < 8) ? row[64 + lane] : 0.f;
  float amax = fmaxf(fabsf(x0), fabsf(x1));
#pragma unroll
  for (int s = 32; s; s >>= 1) amax = fmaxf(amax, __shfl_xor(amax, s));
  const float scale = fmaxf(amax, 1e-8f) / 127.f;
  float y0 = rintf(x0 / scale);
  y0 = fminf(fmaxf(y0, -128.f), 127.f);
  row[lane] = y0 * scale;
  if (lane < 8) {
    float y1 = rintf(x1 / scale);
    y1 = fminf(fmaxf(y1, -128.f), 127.f);
    row[64 + lane] = y1 * scale;
  }
}

// --------- fake-quant v: per (b,h,d) column over 2048 tokens ---------------
__global__ __launch_bounds__(256)
void quant_v(float* __restrict__ qkv) {
  const int col = blockIdx.x;           // 0..2303
  const int d = col % HD_;
  const int h = (col / HD_) % H;
  const int b = col / (HD_ * H);
  float* base = qkv + (size_t)b * Ntok * C3 + 2 * DIMC + h * HD_ + d;
  const int t = threadIdx.x;
  float vals[8];
  float amax = 0.f;
#pragma unroll
  for (int i = 0; i < 8; ++i) {
    float v = base[(size_t)(t + (i << 8)) * C3];
    vals[i] = v;
    amax = fmaxf(amax, fabsf(v));
  }
#pragma unroll
  for (int s = 32; s; s >>= 1) amax = fmaxf(amax, __shfl_xor(amax, s));
  __shared__ float red[4];
  if ((t & 63) == 0) red[t >> 6] = amax;
  __syncthreads();
  amax = fmaxf(fmaxf(red[0], red[1]), fmaxf(red[2], red[3]));
  const float scale = fmaxf(amax, 1e-8f) / 127.f;
#pragma unroll
  for (int i = 0; i < 8; ++i) {
    float y = rintf(vals[i] / scale);
    y = fminf(fmaxf(y, -128.f), 127.f);
    base[(size_t)(t + (i << 8)) * C3] = y * scale;
  }
}

// --------- fused attention: QK^T -> softmax -> uq8 fake-quant -> PV --------
// Block: 256 threads (4 waves), 64 query rows of one (b,h). 32 key tiles of 64.
// Pass A: row max only. Pass B: recompute logits (bit-identical fmaf chain),
// u = rint(255*exp(l-m)), accumulate z and out_raw = sum u*v; final scale
// by 1/(255*Z). Wave w owns rows w*16..w*16+15 (lane = key within tile).
__global__ __launch_bounds__(256)
void attn_kernel(const float* __restrict__ qkv, float* __restrict__ aout) {
  const int bid = blockIdx.x;
  const int qt = bid & 31;
  const int h  = (bid >> 5) & 15;
  const int b  = bid >> 9;
  const int n0 = qt << 6;
  const int t  = threadIdx.x;
  const int lane = t & 63;
  const int wv = t >> 6;

  __shared__ float Qs[64][76];    // stride 304B, 16B aligned
  __shared__ float KVs[64][76];   // K tile, reused for V tile
  __shared__ float Ps[64][65];    // u values (row x key)
  __shared__ float Zs[64];

  const size_t qbase = (size_t)(b * Ntok + n0) * C3 + h * HD_;
  const size_t kbase = (size_t)(b * Ntok) * C3 + DIMC + h * HD_;
  const size_t vbase = (size_t)(b * Ntok) * C3 + 2 * DIMC + h * HD_;

  // load Q tile, pre-scaled by Dh^-0.5 (matches reference q*scale before dot)
  for (int idx = t; idx < 64 * 72; idx += 256) {
    const int r = idx / 72, d = idx - r * 72;
    Qs[r][d] = qkv[qbase + (size_t)r * C3 + d] * 0.11785113019775793f;
  }

  float mrun[16];
#pragma unroll
  for (int i = 0; i < 16; ++i) mrun[i] = -3.4e38f;

  // ---------------- pass A: global row max ----------------
  for (int kt = 0; kt < 32; ++kt) {
    __syncthreads();
    for (int idx = t; idx < 64 * 72; idx += 256) {
      const int r = idx / 72, d = idx - r * 72;
      KVs[r][d] = qkv[kbase + (size_t)(kt * 64 + r) * C3 + d];
    }
    __syncthreads();
    float4 kr[18];
#pragma unroll
    for (int dq = 0; dq < 18; ++dq) kr[dq] = *(const float4*)&KVs[lane][dq << 2];
#pragma unroll
    for (int i = 0; i < 16; ++i) {
      const float* qrow = &Qs[(wv << 4) + i][0];
      float a0 = 0.f, a1 = 0.f, a2 = 0.f, a3 = 0.f;
#pragma unroll
      for (int dq = 0; dq < 18; ++dq) {
        float4 q4 = *(const float4*)&qrow[dq << 2];
        a0 = fmaf(q4.x, kr[dq].x, a0);
        a1 = fmaf(q4.y, kr[dq].y, a1);
        a2 = fmaf(q4.z, kr[dq].z, a2);
        a3 = fmaf(q4.w, kr[dq].w, a3);
      }
      const float l = (a0 + a1) + (a2 + a3);
      mrun[i] = fmaxf(mrun[i], l);
    }
  }
  // reduce max across the wave's 64 key-lanes
#pragma unroll
  for (int i = 0; i < 16; ++i) {
    float m = mrun[i];
#pragma unroll
    for (int s = 32; s; s >>= 1) m = fmaxf(m, __shfl_xor(m, s));
    mrun[i] = m;
  }

  // ---------------- pass B: exp/round + PV ----------------
  float zrun[16];
#pragma unroll
  for (int i = 0; i < 16; ++i) zrun[i] = 0.f;
  float oacc[18];
#pragma unroll
  for (int dd = 0; dd < 18; ++dd) oacc[dd] = 0.f;
  const int pr = t & 63;     // PV phase: row owned by this thread
  const int dg = t >> 6;     // PV phase: d block (18 wide)

  for (int kt = 0; kt < 32; ++kt) {
    __syncthreads();   // prev tile's PV done; safe to overwrite KVs/Ps
    for (int idx = t; idx < 64 * 72; idx += 256) {
      const int r = idx / 72, d = idx - r * 72;
      KVs[r][d] = qkv[kbase + (size_t)(kt * 64 + r) * C3 + d];
    }
    __syncthreads();
    float4 kr[18];
#pragma unroll
    for (int dq = 0; dq < 18; ++dq) kr[dq] = *(const float4*)&KVs[lane][dq << 2];
#pragma unroll
    for (int i = 0; i < 16; ++i) {
      const float* qrow = &Qs[(wv << 4) + i][0];
      float a0 = 0.f, a1 = 0.f, a2 = 0.f, a3 = 0.f;
#pragma unroll
      for (int dq = 0; dq < 18; ++dq) {
        float4 q4 = *(const float4*)&qrow[dq << 2];
        a0 = fmaf(q4.x, kr[dq].x, a0);
        a1 = fmaf(q4.y, kr[dq].y, a1);
        a2 = fmaf(q4.z, kr[dq].z, a2);
        a3 = fmaf(q4.w, kr[dq].w, a3);
      }
      const float l = (a0 + a1) + (a2 + a3);
      const float e = __expf(l - mrun[i]);   // l <= m bitwise -> e <= 1
      zrun[i] += e;
      float u = rintf(e * 255.f);
      u = fminf(u, 255.f);
      Ps[(wv << 4) + i][lane] = u;
    }
    __syncthreads();
    // overwrite K tile with V tile
    for (int idx = t; idx < 64 * 72; idx += 256) {
      const int r = idx / 72, d = idx - r * 72;
      KVs[r][d] = qkv[vbase + (size_t)(kt * 64 + r) * C3 + d];
    }
    __syncthreads();
    // PV: thread (pr, dg) accumulates out_raw[pr][dg*18 .. +17]
#pragma unroll 4
    for (int m_ = 0; m_ < 64; ++m_) {
      const float p = Ps[pr][m_];
      const float* vrow = &KVs[m_][dg * 18];
#pragma unroll
      for (int dd = 0; dd < 18; ++dd)
        oacc[dd] = fmaf(p, vrow[dd], oacc[dd]);
    }
  }

  // Z per row (sum of per-lane partials over the wave), then final scale
#pragma unroll
  for (int i = 0; i < 16; ++i) {
    float z = zrun[i];
#pragma unroll
    for (int s = 32; s; s >>= 1) z += __shfl_xor(z, s);
    if (lane == 0) Zs[(wv << 4) + i] = z;
  }
  __syncthreads();
  const float os = 1.f / (255.f * Zs[pr]);
  float* op = aout + (size_t)(b * Ntok + n0 + pr) * DIMC + h * HD_ + dg * 18;
#pragma unroll
  for (int dd = 0; dd < 18; ++dd) op[dd] = oacc[dd] * os;
}

// ---------------------------------------------------------------------------
extern "C" void kernel_launch(void* const* d_in, const int* in_sizes, int n_in,
                              void* d_out, int out_size, void* d_ws, size_t ws_size,
                              hipStream_t stream) {
  const float* x      = (const float*)d_in[0];
  const float* w_qkv  = (const float*)d_in[1];
  const float* w_proj = (const float*)d_in[2];
  const float* b_proj = (const float*)d_in[3];
  float* out  = (float*)d_out;
  float* qkv  = (float*)d_ws;                       // [4096][3456]
  float* aout = qkv + (size_t)Mrows * C3;           // [4096][1152]

  gemm_bt<false><<<dim3(C3 / 128, Mrows / 128), 256, 0, stream>>>(
      x, w_qkv, nullptr, qkv, Mrows, C3, DIMC);
  quant_qk<<<(Bz * Ntok * 2 * H) / 4, 256, 0, stream>>>(qkv);
  quant_v<<<Bz * H * HD_, 256, 0, stream>>>(qkv);
  attn_kernel<<<Bz * H * (Ntok / 64), 256, 0, stream>>>(qkv, aout);
  gemm_bt<true><<<dim3(DIMC / 128, Mrows / 128), 256, 0, stream>>>(
      aout, w_proj, b_proj, out, Mrows, DIMC, DIMC);
}

// Round 3
// 1102.017 us; speedup vs baseline: 2.2737x; 2.2737x over previous
//
#include <hip/hip_runtime.h>
#include <math.h>

// ---------------------------------------------------------------------------
// QuantizedAttention (round 3): int8-MFMA attention, exact integer arithmetic.
//   k1: qkv = x @ w_qkv^T                  (fp32 GEMM, 128x128, unchanged)
//   k2: quant_qk_pack: per-row amax -> q8/k8 int8 [B,H,N,128] (pad 72->128, zeros)
//       + scales sq/sk [B,H,N]. No fp32 write-back (nothing reads q/k fp32).
//   k3: quant_v_pack: per-(b,h,d) column amax -> vT8 int8 [B,H,80,2048]
//       (d padded 72->80 with zero rows) + sv + colsum (for u-128 correction).
//   k4: attn_mfma: two-pass flash, mfma_i32_16x16x64_i8 for QK^T (exact) and PV.
//       logit l = (sq_i*dh^-0.5)*sk_j*dot_int  (dot exact, cvt exact since <2^24)
//       pass A: row max m (identical float expr in both passes -> e<=1 exact)
//       pass B: u = rint(255*exp(l-m)); PV uses (u-128) i8 + 128*colsum correction;
//       out = (pv_int + 128*colsum)*sv * (1/z)/255  (amax of softmax row == 1/Z).
//       Swapped QK^T (A=K,B=Q): lane owns q-row i=lane&15 -> 4 consecutive key
//       u-bytes per group = one b32 LDS write; PV B-frag = one b128 read/tile.
//       P tile per-wave (16x64B, XOR-swizzled) -> NO __syncthreads in main loop.
//   k5: out = attn_out @ w_proj^T + b_proj  (unchanged)
// jnp.round == half-even -> rintf. Workspace ~98.6 MB.
// ---------------------------------------------------------------------------

typedef int i32x4 __attribute__((ext_vector_type(4)));

constexpr int Bz   = 2;
constexpr int Ntok = 2048;
constexpr int DIMC = 1152;
constexpr int H    = 16;
constexpr int HD_  = 72;
constexpr int Mrows = Bz * Ntok;   // 4096
constexpr int C3    = 3 * DIMC;    // 3456

// ---------------- GEMM: C[m][n] = sum_k A[m][k] * W[n][k] (+ bias[n]) -------
template<bool BIAS>
__global__ __launch_bounds__(256)
void gemm_bt(const float* __restrict__ A, const float* __restrict__ W,
             const float* __restrict__ bias, float* __restrict__ Cout,
             int Md, int Nd, int Kd) {
  __shared__ float As[16][132];
  __shared__ float Bs[16][132];
  const int t  = threadIdx.x;
  const int bm = blockIdx.y << 7, bn = blockIdx.x << 7;
  const int lr = t >> 1;
  const int lk = (t & 1) << 3;
  const float* Ap = A + (size_t)(bm + lr) * Kd + lk;
  const float* Wp = W + (size_t)(bn + lr) * Kd + lk;
  const int tx = t & 15, ty = t >> 4;
  float acc[8][8] = {};
  for (int k0 = 0; k0 < Kd; k0 += 16) {
    float4 a0 = *(const float4*)(Ap + k0);
    float4 a1 = *(const float4*)(Ap + k0 + 4);
    float4 w0 = *(const float4*)(Wp + k0);
    float4 w1 = *(const float4*)(Wp + k0 + 4);
    __syncthreads();
    As[lk + 0][lr] = a0.x; As[lk + 1][lr] = a0.y;
    As[lk + 2][lr] = a0.z; As[lk + 3][lr] = a0.w;
    As[lk + 4][lr] = a1.x; As[lk + 5][lr] = a1.y;
    As[lk + 6][lr] = a1.z; As[lk + 7][lr] = a1.w;
    Bs[lk + 0][lr] = w0.x; Bs[lk + 1][lr] = w0.y;
    Bs[lk + 2][lr] = w0.z; Bs[lk + 3][lr] = w0.w;
    Bs[lk + 4][lr] = w1.x; Bs[lk + 5][lr] = w1.y;
    Bs[lk + 6][lr] = w1.z; Bs[lk + 7][lr] = w1.w;
    __syncthreads();
#pragma unroll
    for (int kk = 0; kk < 16; ++kk) {
      float4 x0 = *(const float4*)&As[kk][(ty << 3) + 0];
      float4 x1 = *(const float4*)&As[kk][(ty << 3) + 4];
      float4 y0 = *(const float4*)&Bs[kk][(tx << 3) + 0];
      float4 y1 = *(const float4*)&Bs[kk][(tx << 3) + 4];
      float ar[8] = {x0.x, x0.y, x0.z, x0.w, x1.x, x1.y, x1.z, x1.w};
      float br[8] = {y0.x, y0.y, y0.z, y0.w, y1.x, y1.y, y1.z, y1.w};
#pragma unroll
      for (int i = 0; i < 8; ++i)
#pragma unroll
        for (int j = 0; j < 8; ++j)
          acc[i][j] = fmaf(ar[i], br[j], acc[i][j]);
    }
  }
  float bias8[8] = {0.f, 0.f, 0.f, 0.f, 0.f, 0.f, 0.f, 0.f};
  if (BIAS) {
#pragma unroll
    for (int j = 0; j < 8; ++j) bias8[j] = bias[bn + (tx << 3) + j];
  }
#pragma unroll
  for (int i = 0; i < 8; ++i) {
    const int m = bm + (ty << 3) + i;
    float* cp = Cout + (size_t)m * Nd + bn + (tx << 3);
    float4 o0, o1;
    o0.x = acc[i][0] + bias8[0]; o0.y = acc[i][1] + bias8[1];
    o0.z = acc[i][2] + bias8[2]; o0.w = acc[i][3] + bias8[3];
    o1.x = acc[i][4] + bias8[4]; o1.y = acc[i][5] + bias8[5];
    o1.z = acc[i][6] + bias8[6]; o1.w = acc[i][7] + bias8[7];
    *(float4*)(cp + 0) = o0;
    *(float4*)(cp + 4) = o1;
  }
}

// --------- quant q,k -> int8 rows (pad 72->128) + scales -------------------
__global__ __launch_bounds__(256)
void quant_qk_pack(const float* __restrict__ qkv,
                   signed char* __restrict__ q8, signed char* __restrict__ k8,
                   float* __restrict__ sq, float* __restrict__ sk) {
  const int wid  = (blockIdx.x << 2) + (threadIdx.x >> 6);  // one wave per row
  const int lane = threadIdx.x & 63;
  const int h  = wid & 15;
  const int g  = (wid >> 4) & 1;        // 0=q, 1=k
  const int bn = wid >> 5;              // 0..4095 = b*2048+n
  const float* row = qkv + (size_t)bn * C3 + g * DIMC + h * HD_;
  float x0 = row[lane];
  float x1 = (lane < 8) ? row[64 + lane] : 0.f;
  float amax = fmaxf(fabsf(x0), fabsf(x1));
#pragma unroll
  for (int s = 32; s; s >>= 1) amax = fmaxf(amax, __shfl_xor(amax, s));
  const float scale = fmaxf(amax, 1e-8f) / 127.f;
  int q0 = (int)fminf(fmaxf(rintf(x0 / scale), -128.f), 127.f);
  int q1 = (int)fminf(fmaxf(rintf(x1 / scale), -128.f), 127.f);
  const int b = bn >> 11, n = bn & 2047;
  signed char* dst = (g ? k8 : q8) + ((size_t)(b * H + h) * Ntok + n) * 128;
  dst[lane] = (signed char)q0;
  dst[64 + lane] = (lane < 8) ? (signed char)q1 : 0;   // zero-pad 72..127
  if (lane == 0) (g ? sk : sq)[(size_t)(b * H + h) * Ntok + n] = scale;
}

// --------- quant v -> int8 transposed [B,H,80,2048] + scale + colsum -------
__global__ __launch_bounds__(256)
void quant_v_pack(const float* __restrict__ qkv, signed char* __restrict__ vT8,
                  float* __restrict__ sv, int* __restrict__ cs) {
  const int col = blockIdx.x;           // 0..2559
  const int d = col % 80;
  const int h = (col / 80) % H;
  const int b = col / (80 * H);
  const int idx = (b * H + h) * 80 + d;
  signed char* vrow = vT8 + (size_t)idx * 2048;
  const int t = threadIdx.x;
  if (d >= HD_) {                       // zero pad rows 72..79
#pragma unroll
    for (int i = 0; i < 8; ++i) vrow[t + (i << 8)] = 0;
    if (t == 0) { sv[idx] = 0.f; cs[idx] = 0; }
    return;
  }
  const float* base = qkv + (size_t)b * Ntok * C3 + 2 * DIMC + h * HD_ + d;
  float vals[8];
  float amax = 0.f;
#pragma unroll
  for (int i = 0; i < 8; ++i) {
    float v = base[(size_t)(t + (i << 8)) * C3];
    vals[i] = v;
    amax = fmaxf(amax, fabsf(v));
  }
#pragma unroll
  for (int s = 32; s; s >>= 1) amax = fmaxf(amax, __shfl_xor(amax, s));
  __shared__ float red[4];
  if ((t & 63) == 0) red[t >> 6] = amax;
  __syncthreads();
  amax = fmaxf(fmaxf(red[0], red[1]), fmaxf(red[2], red[3]));
  const float scale = fmaxf(amax, 1e-8f) / 127.f;
  int isum = 0;
#pragma unroll
  for (int i = 0; i < 8; ++i) {
    int q = (int)fminf(fmaxf(rintf(vals[i] / scale), -128.f), 127.f);
    vrow[t + (i << 8)] = (signed char)q;
    isum += q;
  }
#pragma unroll
  for (int s = 32; s; s >>= 1) isum += __shfl_xor(isum, s);
  __shared__ int ired[4];
  if ((t & 63) == 0) ired[t >> 6] = isum;
  __syncthreads();
  if (t == 0) {
    cs[idx] = ired[0] + ired[1] + ired[2] + ired[3];
    sv[idx] = scale;
  }
}

// --------- int8-MFMA fused attention ---------------------------------------
__device__ __forceinline__ float logitv(float cl, float skj, int a) {
  return cl * skj * (float)a;   // exact cvt (|a|<2^24); identical in both passes
}

__global__ __launch_bounds__(256)
void attn_mfma(const signed char* __restrict__ q8, const signed char* __restrict__ k8,
               const signed char* __restrict__ vT8,
               const float* __restrict__ sq, const float* __restrict__ sk,
               const float* __restrict__ sv, const int* __restrict__ cs,
               float* __restrict__ aout) {
  const int bid = blockIdx.x;
  const int qt = bid & 31, h = (bid >> 5) & 15, b = bid >> 9;
  const int n0 = qt << 6;
  const int t = threadIdx.x, lane = t & 63, wv = t >> 6;
  const int i16 = lane & 15, h4 = lane >> 4;
  const int bh = b * H + h;
  const int sI = (i16 >> 1) & 3;        // XOR-swizzle key (2-way banks = free)

  __shared__ __align__(16) signed char P[4][1024];   // per-wave 16 rows x 64 keys

  // Q fragments (B-operand): lane holds q8[row i16][d = h4*16.. (+c*64)]
  const int qrow = n0 + (wv << 4) + i16;
  const signed char* qp = q8 + ((size_t)bh * Ntok + qrow) * 128 + (h4 << 4);
  const i32x4 qf0 = *(const i32x4*)qp;
  const i32x4 qf1 = *(const i32x4*)(qp + 64);
  const float cl = sq[(size_t)bh * Ntok + qrow] * 0.11785113019775793f;
  const float* skp = sk + (size_t)bh * Ntok;
  const signed char* kp = k8 + (size_t)bh * Ntok * 128 + (h4 << 4);
  const signed char* vp = vT8 + (size_t)bh * 80 * 2048 + (h4 << 4);

  // ---------------- pass A: global row max ----------------
  float mrow = -3.4e38f;
  for (int kt = 0; kt < 32; ++kt) {
#pragma unroll
    for (int g = 0; g < 4; ++g) {
      const signed char* kr = kp + (size_t)(kt * 64 + g * 16 + i16) * 128;
      i32x4 kf0 = *(const i32x4*)kr;
      i32x4 kf1 = *(const i32x4*)(kr + 64);
      i32x4 acc = {0, 0, 0, 0};
      acc = __builtin_amdgcn_mfma_i32_16x16x64_i8(kf0, qf0, acc, 0, 0, 0);
      acc = __builtin_amdgcn_mfma_i32_16x16x64_i8(kf1, qf1, acc, 0, 0, 0);
      const float4 skv = *(const float4*)(skp + kt * 64 + g * 16 + (h4 << 2));
      mrow = fmaxf(mrow, logitv(cl, skv.x, acc[0]));
      mrow = fmaxf(mrow, logitv(cl, skv.y, acc[1]));
      mrow = fmaxf(mrow, logitv(cl, skv.z, acc[2]));
      mrow = fmaxf(mrow, logitv(cl, skv.w, acc[3]));
    }
  }
  mrow = fmaxf(mrow, __shfl_xor(mrow, 16));
  mrow = fmaxf(mrow, __shfl_xor(mrow, 32));

  // ---------------- pass B: exp/round + PV ----------------
  float zacc = 0.f;
  i32x4 pv[5];
#pragma unroll
  for (int dg = 0; dg < 5; ++dg) pv[dg] = (i32x4){0, 0, 0, 0};

  for (int kt = 0; kt < 32; ++kt) {
#pragma unroll
    for (int g = 0; g < 4; ++g) {
      const signed char* kr = kp + (size_t)(kt * 64 + g * 16 + i16) * 128;
      i32x4 kf0 = *(const i32x4*)kr;
      i32x4 kf1 = *(const i32x4*)(kr + 64);
      i32x4 acc = {0, 0, 0, 0};
      acc = __builtin_amdgcn_mfma_i32_16x16x64_i8(kf0, qf0, acc, 0, 0, 0);
      acc = __builtin_amdgcn_mfma_i32_16x16x64_i8(kf1, qf1, acc, 0, 0, 0);
      const float4 skv = *(const float4*)(skp + kt * 64 + g * 16 + (h4 << 2));
      float sks[4] = {skv.x, skv.y, skv.z, skv.w};
      int packed = 0;
#pragma unroll
      for (int r = 0; r < 4; ++r) {
        const float lv = logitv(cl, sks[r], acc[r]);
        const float e = __expf(lv - mrow);      // lv <= mrow bitwise -> e <= 1
        zacc += e;
        const float u = fminf(rintf(e * 255.f), 255.f);
        const int s8 = (int)u - 128;            // fits signed i8
        packed |= (s8 & 255) << (r << 3);
      }
      // P[i16][g*16 + h4*4 .. +3] with col-block XOR swizzle
      *(int*)&P[wv][(i16 << 6) + ((g ^ sI) << 4) + (h4 << 2)] = packed;
    }
    // PV B-frag: P[i16][h4*16 .. +15] (swizzled)
    const i32x4 pf = *(const i32x4*)&P[wv][(i16 << 6) + ((h4 ^ sI) << 4)];
#pragma unroll
    for (int dg = 0; dg < 5; ++dg) {
      const i32x4 vf = *(const i32x4*)(vp + (size_t)(dg * 16 + i16) * 2048 + kt * 64);
      pv[dg] = __builtin_amdgcn_mfma_i32_16x16x64_i8(vf, pf, pv[dg], 0, 0, 0);
    }
  }

  // ---------------- epilogue ----------------
  float z = zacc;
  z += __shfl_xor(z, 16);
  z += __shfl_xor(z, 32);
  const float rz = 1.0f / z;            // == amax of softmax row (exactly fl(1/Z))
  const float ss = rz / 255.f;          // reference's quant scale

  float* op = aout + ((size_t)(b * Ntok + n0 + (wv << 4) + i16)) * DIMC + h * HD_;
  const int sbase = bh * 80;
#pragma unroll
  for (int dg = 0; dg < 5; ++dg) {
    const int d0 = dg * 16 + (h4 << 2);
    if (d0 < HD_) {                     // dg==4: only h4<2 stores (d0=64,68)
      float4 o;
      int t0 = pv[dg][0] + (cs[sbase + d0 + 0] << 7);
      int t1 = pv[dg][1] + (cs[sbase + d0 + 1] << 7);
      int t2 = pv[dg][2] + (cs[sbase + d0 + 2] << 7);
      int t3 = pv[dg][3] + (cs[sbase + d0 + 3] << 7);
      o.x = (float)t0 * sv[sbase + d0 + 0] * ss;
      o.y = (float)t1 * sv[sbase + d0 + 1] * ss;
      o.z = (float)t2 * sv[sbase + d0 + 2] * ss;
      o.w = (float)t3 * sv[sbase + d0 + 3] * ss;
      *(float4*)(op + d0) = o;
    }
  }
}

// ---------------------------------------------------------------------------
constexpr size_t SZ_QKV  = (size_t)Mrows * C3 * 4;       // 56,623,104
constexpr size_t SZ_AOUT = (size_t)Mrows * DIMC * 4;     // 18,874,368
constexpr size_t SZ_Q8   = (size_t)Bz * H * Ntok * 128;  //  8,388,608
constexpr size_t SZ_V8   = (size_t)Bz * H * 80 * 2048;   //  5,242,880
constexpr size_t SZ_S    = (size_t)Bz * H * Ntok * 4;    //    524,288
constexpr size_t SZ_SV   = (size_t)Bz * H * 80 * 4;      //     10,240
constexpr size_t OFF_AOUT = SZ_QKV;
constexpr size_t OFF_Q8   = OFF_AOUT + SZ_AOUT;
constexpr size_t OFF_K8   = OFF_Q8 + SZ_Q8;
constexpr size_t OFF_V8   = OFF_K8 + SZ_Q8;
constexpr size_t OFF_SQ   = OFF_V8 + SZ_V8;
constexpr size_t OFF_SK   = OFF_SQ + SZ_S;
constexpr size_t OFF_SV   = OFF_SK + SZ_S;
constexpr size_t OFF_CS   = OFF_SV + SZ_SV;              // end ~98.6 MB

extern "C" void kernel_launch(void* const* d_in, const int* in_sizes, int n_in,
                              void* d_out, int out_size, void* d_ws, size_t ws_size,
                              hipStream_t stream) {
  const float* x      = (const float*)d_in[0];
  const float* w_qkv  = (const float*)d_in[1];
  const float* w_proj = (const float*)d_in[2];
  const float* b_proj = (const float*)d_in[3];
  float* out = (float*)d_out;
  char* ws = (char*)d_ws;
  float* qkv  = (float*)ws;
  float* aout = (float*)(ws + OFF_AOUT);
  signed char* q8  = (signed char*)(ws + OFF_Q8);
  signed char* k8  = (signed char*)(ws + OFF_K8);
  signed char* vT8 = (signed char*)(ws + OFF_V8);
  float* sq = (float*)(ws + OFF_SQ);
  float* sk = (float*)(ws + OFF_SK);
  float* sv = (float*)(ws + OFF_SV);
  int*   cs = (int*)(ws + OFF_CS);

  gemm_bt<false><<<dim3(C3 / 128, Mrows / 128), 256, 0, stream>>>(
      x, w_qkv, nullptr, qkv, Mrows, C3, DIMC);
  quant_qk_pack<<<(Bz * Ntok * 2 * H) / 4, 256, 0, stream>>>(qkv, q8, k8, sq, sk);
  quant_v_pack<<<Bz * H * 80, 256, 0, stream>>>(qkv, vT8, sv, cs);
  attn_mfma<<<Bz * H * (Ntok / 64), 256, 0, stream>>>(q8, k8, vT8, sq, sk, sv, cs, aout);
  gemm_bt<true><<<dim3(DIMC / 128, Mrows / 128), 256, 0, stream>>>(
      aout, w_proj, b_proj, out, Mrows, DIMC, DIMC);
}

// Round 5
// 730.587 us; speedup vs baseline: 3.4297x; 1.5084x over previous
//
#include <hip/hip_runtime.h>
#include <math.h>

// ---------------------------------------------------------------------------
// QuantizedAttention (round 5 = round 4 + LDS-alignment hardening):
//   split3: fp32 -> 3 bf16 planes (h,m,l), residuals exact; sum = x + O(2^-27).
//   gemm3:  C = sum of 6 bf16 MFMA products (hh,hm,mh,hl,lh,mm) == fp32 GEMM
//           to ~2^-27 rel. 128x128 tile, 4 waves, BK=32, global_load_lds(16),
//           3+3 plane tiles in 48KB LDS, 2-barrier K-loop, XCD-swizzled blocks.
//   quant kernels + attn_mfma unchanged from round 3 (exact int8 path);
//   attn epilogue writes 3 bf16 planes of its output directly (feeds proj gemm3).
//   Fallback to round-3 fp32-vector-GEMM path if ws_size too small.
// jnp.round == half-even -> rintf. New-path workspace 116.8 MB (aliased).
// ---------------------------------------------------------------------------

typedef int   i32x4  __attribute__((ext_vector_type(4)));
typedef short bf16x8 __attribute__((ext_vector_type(8)));
typedef float f32x4  __attribute__((ext_vector_type(4)));

constexpr int Bz   = 2;
constexpr int Ntok = 2048;
constexpr int DIMC = 1152;
constexpr int H    = 16;
constexpr int HD_  = 72;
constexpr int Mrows = Bz * Ntok;   // 4096
constexpr int C3    = 3 * DIMC;    // 3456

// ---------------- bf16 split helpers ---------------------------------------
__device__ __forceinline__ unsigned short f2bf(float f) {
  unsigned u = __float_as_uint(f);
  return (unsigned short)((u + 0x7fffu + ((u >> 16) & 1u)) >> 16);   // RNE
}
__device__ __forceinline__ float bf2f(unsigned short h) {
  return __uint_as_float((unsigned)h << 16);
}
__device__ __forceinline__ void split1(float v, unsigned short& h,
                                       unsigned short& m, unsigned short& l) {
  h = f2bf(v); float r1 = v - bf2f(h);      // exact
  m = f2bf(r1); float r2 = r1 - bf2f(m);    // exact
  l = f2bf(r2);
}

__global__ __launch_bounds__(256)
void split3_kernel(const float* __restrict__ src, unsigned short* __restrict__ ph,
                   unsigned short* __restrict__ pm, unsigned short* __restrict__ pl,
                   int n4) {
  for (int i = blockIdx.x * 256 + threadIdx.x; i < n4; i += gridDim.x * 256) {
    float4 v = ((const float4*)src)[i];
    ushort4 h, m, l;
    split1(v.x, h.x, m.x, l.x);
    split1(v.y, h.y, m.y, l.y);
    split1(v.z, h.z, m.z, l.z);
    split1(v.w, h.w, m.w, l.w);
    ((ushort4*)ph)[i] = h;
    ((ushort4*)pm)[i] = m;
    ((ushort4*)pl)[i] = l;
  }
}

// ---------------- bf16x3 MFMA GEMM -----------------------------------------
__device__ __forceinline__ void gload16(const void* g, void* l) {
  __builtin_amdgcn_global_load_lds(
      (const __attribute__((address_space(1))) unsigned int*)g,
      (__attribute__((address_space(3))) unsigned int*)l, 16, 0, 0);
}

// C[m][n] = sum_k A(m,k)*W(n,k) (+bias), A/W given as 3 bf16 planes [rows][Kd].
template<bool BIAS>
__global__ __launch_bounds__(256)
void gemm3(const unsigned short* __restrict__ Ah, const unsigned short* __restrict__ Am,
           const unsigned short* __restrict__ Al,
           const unsigned short* __restrict__ Bh, const unsigned short* __restrict__ Bm,
           const unsigned short* __restrict__ Bl,
           const float* __restrict__ bias, float* __restrict__ C,
           int Md, int Nd, int Kd) {
  __shared__ __align__(16) unsigned short As[3][128 * 32];
  __shared__ __align__(16) unsigned short Bs[3][128 * 32];
  const int t = threadIdx.x, lane = t & 63, wv = t >> 6;
  const int r15 = lane & 15, h4 = lane >> 4;
  // XCD-aware bijective block remap (m204 form)
  const int gx = gridDim.x;
  const int nwg = gx * gridDim.y;
  const int orig = blockIdx.y * gx + blockIdx.x;
  const int qq = nwg >> 3, rr = nwg & 7;
  const int xcd = orig & 7, loc = orig >> 3;
  const int wg = (xcd < rr) ? (xcd * (qq + 1) + loc)
                            : (rr * (qq + 1) + (xcd - rr) * qq + loc);
  const int bm = (wg / gx) << 7, bn = (wg % gx) << 7;
  const int wn = (wv & 1) << 6, wm = (wv >> 1) << 6;

  const unsigned short* Ap[3] = {Ah, Am, Al};
  const unsigned short* Bp[3] = {Bh, Bm, Bl};

  f32x4 acc[4][4];
#pragma unroll
  for (int i = 0; i < 4; ++i)
#pragma unroll
    for (int j = 0; j < 4; ++j) acc[i][j] = (f32x4){0.f, 0.f, 0.f, 0.f};

  const int lin0 = t * 16;            // linear LDS byte offset (wave-contiguous)
  const int r0 = lin0 >> 6, cb0 = lin0 & 63;
  const int lin1 = lin0 + 4096;
  const int r1 = lin1 >> 6, cb1 = lin1 & 63;

  for (int k0 = 0; k0 < Kd; k0 += 32) {
    __syncthreads();                  // previous step's compute done
#pragma unroll
    for (int p = 0; p < 3; ++p) {
      gload16((const char*)(Ap[p] + (size_t)(bm + r0) * Kd + k0) + cb0,
              (char*)&As[p][0] + lin0);
      gload16((const char*)(Ap[p] + (size_t)(bm + r1) * Kd + k0) + cb1,
              (char*)&As[p][0] + lin1);
      gload16((const char*)(Bp[p] + (size_t)(bn + r0) * Kd + k0) + cb0,
              (char*)&Bs[p][0] + lin0);
      gload16((const char*)(Bp[p] + (size_t)(bn + r1) * Kd + k0) + cb1,
              (char*)&Bs[p][0] + lin1);
    }
    __syncthreads();                  // drains vmcnt before use
    bf16x8 bf[3][4];
#pragma unroll
    for (int p = 0; p < 3; ++p)
#pragma unroll
      for (int c = 0; c < 4; ++c)
        bf[p][c] = *(const bf16x8*)&Bs[p][(wn + c * 16 + r15) * 32 + h4 * 8];
#pragma unroll
    for (int pa = 0; pa < 3; ++pa) {
#pragma unroll
      for (int mf = 0; mf < 4; ++mf) {
        bf16x8 af = *(const bf16x8*)&As[pa][(wm + mf * 16 + r15) * 32 + h4 * 8];
#pragma unroll
        for (int bp = 0; bp < 3; ++bp) {
          if (bp < 3 - pa) {          // pairs: h*{h,m,l}, m*{h,m}, l*{h}
#pragma unroll
            for (int nf = 0; nf < 4; ++nf)
              acc[mf][nf] = __builtin_amdgcn_mfma_f32_16x16x32_bf16(
                  bf[bp][nf], af, acc[mf][nf], 0, 0, 0);
          }
        }
      }
    }
  }
  // epilogue: D col(lane&15)=m, row((lane>>4)*4+reg)=n -> float4 along n
#pragma unroll
  for (int mf = 0; mf < 4; ++mf) {
    const int m = bm + wm + mf * 16 + r15;
#pragma unroll
    for (int nf = 0; nf < 4; ++nf) {
      const int n = bn + wn + nf * 16 + (h4 << 2);
      float4 o;
      o.x = acc[mf][nf][0]; o.y = acc[mf][nf][1];
      o.z = acc[mf][nf][2]; o.w = acc[mf][nf][3];
      if (BIAS) {
        o.x += bias[n]; o.y += bias[n + 1]; o.z += bias[n + 2]; o.w += bias[n + 3];
      }
      *(float4*)(C + (size_t)m * Nd + n) = o;
    }
  }
}

// ---------------- fp32 vector GEMM (fallback path only) ---------------------
template<bool BIAS>
__global__ __launch_bounds__(256)
void gemm_bt(const float* __restrict__ A, const float* __restrict__ W,
             const float* __restrict__ bias, float* __restrict__ Cout,
             int Md, int Nd, int Kd) {
  __shared__ float As[16][132];
  __shared__ float Bs[16][132];
  const int t  = threadIdx.x;
  const int bm = blockIdx.y << 7, bn = blockIdx.x << 7;
  const int lr = t >> 1;
  const int lk = (t & 1) << 3;
  const float* Ap = A + (size_t)(bm + lr) * Kd + lk;
  const float* Wp = W + (size_t)(bn + lr) * Kd + lk;
  const int tx = t & 15, ty = t >> 4;
  float acc[8][8] = {};
  for (int k0 = 0; k0 < Kd; k0 += 16) {
    float4 a0 = *(const float4*)(Ap + k0);
    float4 a1 = *(const float4*)(Ap + k0 + 4);
    float4 w0 = *(const float4*)(Wp + k0);
    float4 w1 = *(const float4*)(Wp + k0 + 4);
    __syncthreads();
    As[lk + 0][lr] = a0.x; As[lk + 1][lr] = a0.y;
    As[lk + 2][lr] = a0.z; As[lk + 3][lr] = a0.w;
    As[lk + 4][lr] = a1.x; As[lk + 5][lr] = a1.y;
    As[lk + 6][lr] = a1.z; As[lk + 7][lr] = a1.w;
    Bs[lk + 0][lr] = w0.x; Bs[lk + 1][lr] = w0.y;
    Bs[lk + 2][lr] = w0.z; Bs[lk + 3][lr] = w0.w;
    Bs[lk + 4][lr] = w1.x; Bs[lk + 5][lr] = w1.y;
    Bs[lk + 6][lr] = w1.z; Bs[lk + 7][lr] = w1.w;
    __syncthreads();
#pragma unroll
    for (int kk = 0; kk < 16; ++kk) {
      float4 x0 = *(const float4*)&As[kk][(ty << 3) + 0];
      float4 x1 = *(const float4*)&As[kk][(ty << 3) + 4];
      float4 y0 = *(const float4*)&Bs[kk][(tx << 3) + 0];
      float4 y1 = *(const float4*)&Bs[kk][(tx << 3) + 4];
      float ar[8] = {x0.x, x0.y, x0.z, x0.w, x1.x, x1.y, x1.z, x1.w};
      float br[8] = {y0.x, y0.y, y0.z, y0.w, y1.x, y1.y, y1.z, y1.w};
#pragma unroll
      for (int i = 0; i < 8; ++i)
#pragma unroll
        for (int j = 0; j < 8; ++j)
          acc[i][j] = fmaf(ar[i], br[j], acc[i][j]);
    }
  }
  float bias8[8] = {0.f, 0.f, 0.f, 0.f, 0.f, 0.f, 0.f, 0.f};
  if (BIAS) {
#pragma unroll
    for (int j = 0; j < 8; ++j) bias8[j] = bias[bn + (tx << 3) + j];
  }
#pragma unroll
  for (int i = 0; i < 8; ++i) {
    const int m = bm + (ty << 3) + i;
    float* cp = Cout + (size_t)m * Nd + bn + (tx << 3);
    float4 o0, o1;
    o0.x = acc[i][0] + bias8[0]; o0.y = acc[i][1] + bias8[1];
    o0.z = acc[i][2] + bias8[2]; o0.w = acc[i][3] + bias8[3];
    o1.x = acc[i][4] + bias8[4]; o1.y = acc[i][5] + bias8[5];
    o1.z = acc[i][6] + bias8[6]; o1.w = acc[i][7] + bias8[7];
    *(float4*)(cp + 0) = o0;
    *(float4*)(cp + 4) = o1;
  }
}

// --------- quant q,k -> int8 rows (pad 72->128) + scales -------------------
__global__ __launch_bounds__(256)
void quant_qk_pack(const float* __restrict__ qkv,
                   signed char* __restrict__ q8, signed char* __restrict__ k8,
                   float* __restrict__ sq, float* __restrict__ sk) {
  const int wid  = (blockIdx.x << 2) + (threadIdx.x >> 6);  // one wave per row
  const int lane = threadIdx.x & 63;
  const int h  = wid & 15;
  const int g  = (wid >> 4) & 1;        // 0=q, 1=k
  const int bn = wid >> 5;              // 0..4095 = b*2048+n
  const float* row = qkv + (size_t)bn * C3 + g * DIMC + h * HD_;
  float x0 = row[lane];
  float x1 = (lane < 8) ? row[64 + lane] : 0.f;
  float amax = fmaxf(fabsf(x0), fabsf(x1));
#pragma unroll
  for (int s = 32; s; s >>= 1) amax = fmaxf(amax, __shfl_xor(amax, s));
  const float scale = fmaxf(amax, 1e-8f) / 127.f;
  int q0 = (int)fminf(fmaxf(rintf(x0 / scale), -128.f), 127.f);
  int q1 = (int)fminf(fmaxf(rintf(x1 / scale), -128.f), 127.f);
  const int b = bn >> 11, n = bn & 2047;
  signed char* dst = (g ? k8 : q8) + ((size_t)(b * H + h) * Ntok + n) * 128;
  dst[lane] = (signed char)q0;
  dst[64 + lane] = (lane < 8) ? (signed char)q1 : 0;   // zero-pad 72..127
  if (lane == 0) (g ? sk : sq)[(size_t)(b * H + h) * Ntok + n] = scale;
}

// --------- quant v -> int8 transposed [B,H,80,2048] + scale + colsum -------
__global__ __launch_bounds__(256)
void quant_v_pack(const float* __restrict__ qkv, signed char* __restrict__ vT8,
                  float* __restrict__ sv, int* __restrict__ cs) {
  const int col = blockIdx.x;           // 0..2559
  const int d = col % 80;
  const int h = (col / 80) % H;
  const int b = col / (80 * H);
  const int idx = (b * H + h) * 80 + d;
  signed char* vrow = vT8 + (size_t)idx * 2048;
  const int t = threadIdx.x;
  if (d >= HD_) {                       // zero pad rows 72..79
#pragma unroll
    for (int i = 0; i < 8; ++i) vrow[t + (i << 8)] = 0;
    if (t == 0) { sv[idx] = 0.f; cs[idx] = 0; }
    return;
  }
  const float* base = qkv + (size_t)b * Ntok * C3 + 2 * DIMC + h * HD_ + d;
  float vals[8];
  float amax = 0.f;
#pragma unroll
  for (int i = 0; i < 8; ++i) {
    float v = base[(size_t)(t + (i << 8)) * C3];
    vals[i] = v;
    amax = fmaxf(amax, fabsf(v));
  }
#pragma unroll
  for (int s = 32; s; s >>= 1) amax = fmaxf(amax, __shfl_xor(amax, s));
  __shared__ float red[4];
  if ((t & 63) == 0) red[t >> 6] = amax;
  __syncthreads();
  amax = fmaxf(fmaxf(red[0], red[1]), fmaxf(red[2], red[3]));
  const float scale = fmaxf(amax, 1e-8f) / 127.f;
  int isum = 0;
#pragma unroll
  for (int i = 0; i < 8; ++i) {
    int q = (int)fminf(fmaxf(rintf(vals[i] / scale), -128.f), 127.f);
    vrow[t + (i << 8)] = (signed char)q;
    isum += q;
  }
#pragma unroll
  for (int s = 32; s; s >>= 1) isum += __shfl_xor(isum, s);
  __shared__ int ired[4];
  if ((t & 63) == 0) ired[t >> 6] = isum;
  __syncthreads();
  if (t == 0) {
    cs[idx] = ired[0] + ired[1] + ired[2] + ired[3];
    sv[idx] = scale;
  }
}

// --------- int8-MFMA fused attention ---------------------------------------
__device__ __forceinline__ float logitv(float cl, float skj, int a) {
  return cl * skj * (float)a;   // exact cvt (|a|<2^24); identical in both passes
}

template<bool SPLIT>
__global__ __launch_bounds__(256)
void attn_mfma(const signed char* __restrict__ q8, const signed char* __restrict__ k8,
               const signed char* __restrict__ vT8,
               const float* __restrict__ sq, const float* __restrict__ sk,
               const float* __restrict__ sv, const int* __restrict__ cs,
               float* __restrict__ aoutF,
               unsigned short* __restrict__ ah, unsigned short* __restrict__ am,
               unsigned short* __restrict__ al) {
  const int bid = blockIdx.x;
  const int qt = bid & 31, h = (bid >> 5) & 15, b = bid >> 9;
  const int n0 = qt << 6;
  const int t = threadIdx.x, lane = t & 63, wv = t >> 6;
  const int i16 = lane & 15, h4 = lane >> 4;
  const int bh = b * H + h;
  const int sI = (i16 >> 1) & 3;        // XOR-swizzle key (2-way banks = free)

  __shared__ __align__(16) signed char P[4][1024];   // per-wave 16 rows x 64 keys

  // Q fragments (B-operand): lane holds q8[row i16][d = h4*16.. (+c*64)]
  const int qrow = n0 + (wv << 4) + i16;
  const signed char* qp = q8 + ((size_t)bh * Ntok + qrow) * 128 + (h4 << 4);
  const i32x4 qf0 = *(const i32x4*)qp;
  const i32x4 qf1 = *(const i32x4*)(qp + 64);
  const float cl = sq[(size_t)bh * Ntok + qrow] * 0.11785113019775793f;
  const float* skp = sk + (size_t)bh * Ntok;
  const signed char* kp = k8 + (size_t)bh * Ntok * 128 + (h4 << 4);
  const signed char* vp = vT8 + (size_t)bh * 80 * 2048 + (h4 << 4);

  // ---------------- pass A: global row max ----------------
  float mrow = -3.4e38f;
  for (int kt = 0; kt < 32; ++kt) {
#pragma unroll
    for (int g = 0; g < 4; ++g) {
      const signed char* kr = kp + (size_t)(kt * 64 + g * 16 + i16) * 128;
      i32x4 kf0 = *(const i32x4*)kr;
      i32x4 kf1 = *(const i32x4*)(kr + 64);
      i32x4 acc = {0, 0, 0, 0};
      acc = __builtin_amdgcn_mfma_i32_16x16x64_i8(kf0, qf0, acc, 0, 0, 0);
      acc = __builtin_amdgcn_mfma_i32_16x16x64_i8(kf1, qf1, acc, 0, 0, 0);
      const float4 skv = *(const float4*)(skp + kt * 64 + g * 16 + (h4 << 2));
      mrow = fmaxf(mrow, logitv(cl, skv.x, acc[0]));
      mrow = fmaxf(mrow, logitv(cl, skv.y, acc[1]));
      mrow = fmaxf(mrow, logitv(cl, skv.z, acc[2]));
      mrow = fmaxf(mrow, logitv(cl, skv.w, acc[3]));
    }
  }
  mrow = fmaxf(mrow, __shfl_xor(mrow, 16));
  mrow = fmaxf(mrow, __shfl_xor(mrow, 32));

  // ---------------- pass B: exp/round + PV ----------------
  float zacc = 0.f;
  i32x4 pv[5];
#pragma unroll
  for (int dg = 0; dg < 5; ++dg) pv[dg] = (i32x4){0, 0, 0, 0};

  for (int kt = 0; kt < 32; ++kt) {
#pragma unroll
    for (int g = 0; g < 4; ++g) {
      const signed char* kr = kp + (size_t)(kt * 64 + g * 16 + i16) * 128;
      i32x4 kf0 = *(const i32x4*)kr;
      i32x4 kf1 = *(const i32x4*)(kr + 64);
      i32x4 acc = {0, 0, 0, 0};
      acc = __builtin_amdgcn_mfma_i32_16x16x64_i8(kf0, qf0, acc, 0, 0, 0);
      acc = __builtin_amdgcn_mfma_i32_16x16x64_i8(kf1, qf1, acc, 0, 0, 0);
      const float4 skv = *(const float4*)(skp + kt * 64 + g * 16 + (h4 << 2));
      float sks[4] = {skv.x, skv.y, skv.z, skv.w};
      int packed = 0;
#pragma unroll
      for (int r = 0; r < 4; ++r) {
        const float lv = logitv(cl, sks[r], acc[r]);
        const float e = __expf(lv - mrow);      // lv <= mrow bitwise -> e <= 1
        zacc += e;
        const float u = fminf(rintf(e * 255.f), 255.f);
        const int s8 = (int)u - 128;            // fits signed i8
        packed |= (s8 & 255) << (r << 3);
      }
      *(int*)&P[wv][(i16 << 6) + ((g ^ sI) << 4) + (h4 << 2)] = packed;
    }
    const i32x4 pf = *(const i32x4*)&P[wv][(i16 << 6) + ((h4 ^ sI) << 4)];
#pragma unroll
    for (int dg = 0; dg < 5; ++dg) {
      const i32x4 vf = *(const i32x4*)(vp + (size_t)(dg * 16 + i16) * 2048 + kt * 64);
      pv[dg] = __builtin_amdgcn_mfma_i32_16x16x64_i8(vf, pf, pv[dg], 0, 0, 0);
    }
  }

  // ---------------- epilogue ----------------
  float z = zacc;
  z += __shfl_xor(z, 16);
  z += __shfl_xor(z, 32);
  const float rz = 1.0f / z;
  const float ss = rz / 255.f;

  const size_t rowoff = ((size_t)(b * Ntok + n0 + (wv << 4) + i16)) * DIMC + h * HD_;
  const int sbase = bh * 80;
#pragma unroll
  for (int dg = 0; dg < 5; ++dg) {
    const int d0 = dg * 16 + (h4 << 2);
    if (d0 < HD_) {
      float4 o;
      int t0 = pv[dg][0] + (cs[sbase + d0 + 0] << 7);
      int t1 = pv[dg][1] + (cs[sbase + d0 + 1] << 7);
      int t2 = pv[dg][2] + (cs[sbase + d0 + 2] << 7);
      int t3 = pv[dg][3] + (cs[sbase + d0 + 3] << 7);
      o.x = (float)t0 * sv[sbase + d0 + 0] * ss;
      o.y = (float)t1 * sv[sbase + d0 + 1] * ss;
      o.z = (float)t2 * sv[sbase + d0 + 2] * ss;
      o.w = (float)t3 * sv[sbase + d0 + 3] * ss;
      if (SPLIT) {
        ushort4 hh, mm, ll;
        split1(o.x, hh.x, mm.x, ll.x);
        split1(o.y, hh.y, mm.y, ll.y);
        split1(o.z, hh.z, mm.z, ll.z);
        split1(o.w, hh.w, mm.w, ll.w);
        *(ushort4*)(ah + rowoff + d0) = hh;
        *(ushort4*)(am + rowoff + d0) = mm;
        *(ushort4*)(al + rowoff + d0) = ll;
      } else {
        *(float4*)(aoutF + rowoff + d0) = o;
      }
    }
  }
}

// ---------------------------------------------------------------------------
// New-path workspace layout (aliased):
constexpr size_t SZ_QKV  = (size_t)Mrows * C3 * 4;        // 56,623,104
constexpr size_t PL_X    = (size_t)Mrows * DIMC * 2;      //  9,437,184 (x/a plane)
constexpr size_t PL_WQ   = (size_t)C3 * DIMC * 2;         //  7,962,624
constexpr size_t PL_WP   = (size_t)DIMC * DIMC * 2;       //  2,654,208
constexpr size_t OFF_XA  = SZ_QKV;                        // x-planes, later a-planes
constexpr size_t OFF_WQ  = OFF_XA + 3 * PL_X;             // wq-planes, later int8 bufs
constexpr size_t OFF_WP  = OFF_WQ + 3 * PL_WQ;
constexpr size_t REQ_NEW = OFF_WP + 3 * PL_WP;            // 116,785,152
// int8/scale aliases inside WQ region (WQ dead after qkv-gemm):
constexpr size_t SZ_Q8 = (size_t)Bz * H * Ntok * 128;     // 8,388,608
constexpr size_t SZ_V8 = (size_t)Bz * H * 80 * 2048;      // 5,242,880
constexpr size_t SZ_S  = (size_t)Bz * H * Ntok * 4;       //   524,288
constexpr size_t SZ_SV = (size_t)Bz * H * 80 * 4;         //    10,240
constexpr size_t A_Q8 = OFF_WQ;
constexpr size_t A_K8 = A_Q8 + SZ_Q8;
constexpr size_t A_V8 = A_K8 + SZ_Q8;
constexpr size_t A_SQ = A_V8 + SZ_V8;
constexpr size_t A_SK = A_SQ + SZ_S;
constexpr size_t A_SV = A_SK + SZ_S;
constexpr size_t A_CS = A_SV + SZ_SV;
static_assert(A_CS + SZ_SV <= OFF_WP, "alias overflow");
// Fallback (round-3) layout:
constexpr size_t F_AOUT = SZ_QKV;
constexpr size_t F_Q8   = F_AOUT + (size_t)Mrows * DIMC * 4;
constexpr size_t F_K8   = F_Q8 + SZ_Q8;
constexpr size_t F_V8   = F_K8 + SZ_Q8;
constexpr size_t F_SQ   = F_V8 + SZ_V8;
constexpr size_t F_SK   = F_SQ + SZ_S;
constexpr size_t F_SV   = F_SK + SZ_S;
constexpr size_t F_CS   = F_SV + SZ_SV;

extern "C" void kernel_launch(void* const* d_in, const int* in_sizes, int n_in,
                              void* d_out, int out_size, void* d_ws, size_t ws_size,
                              hipStream_t stream) {
  const float* x      = (const float*)d_in[0];
  const float* w_qkv  = (const float*)d_in[1];
  const float* w_proj = (const float*)d_in[2];
  const float* b_proj = (const float*)d_in[3];
  float* out = (float*)d_out;
  char* ws = (char*)d_ws;
  float* qkv = (float*)ws;

  if (ws_size >= REQ_NEW) {
    unsigned short* xh = (unsigned short*)(ws + OFF_XA);
    unsigned short* xm = xh + PL_X / 2;
    unsigned short* xl = xm + PL_X / 2;
    unsigned short* wqh = (unsigned short*)(ws + OFF_WQ);
    unsigned short* wqm = wqh + PL_WQ / 2;
    unsigned short* wql = wqm + PL_WQ / 2;
    unsigned short* wph = (unsigned short*)(ws + OFF_WP);
    unsigned short* wpm = wph + PL_WP / 2;
    unsigned short* wpl = wpm + PL_WP / 2;
    signed char* q8  = (signed char*)(ws + A_Q8);
    signed char* k8  = (signed char*)(ws + A_K8);
    signed char* vT8 = (signed char*)(ws + A_V8);
    float* sq = (float*)(ws + A_SQ);
    float* sk = (float*)(ws + A_SK);
    float* sv = (float*)(ws + A_SV);
    int*   cs = (int*)(ws + A_CS);
    // a-planes alias x-planes (x dead after qkv-gemm; attn writes them)
    unsigned short* ah = xh;
    unsigned short* am = xm;
    unsigned short* al = xl;

    split3_kernel<<<2048, 256, 0, stream>>>(x, xh, xm, xl, Mrows * DIMC / 4);
    split3_kernel<<<2048, 256, 0, stream>>>(w_qkv, wqh, wqm, wql, C3 * DIMC / 4);
    split3_kernel<<<1297, 256, 0, stream>>>(w_proj, wph, wpm, wpl, DIMC * DIMC / 4);
    gemm3<false><<<dim3(C3 / 128, Mrows / 128), 256, 0, stream>>>(
        xh, xm, xl, wqh, wqm, wql, nullptr, qkv, Mrows, C3, DIMC);
    quant_qk_pack<<<(Bz * Ntok * 2 * H) / 4, 256, 0, stream>>>(qkv, q8, k8, sq, sk);
    quant_v_pack<<<Bz * H * 80, 256, 0, stream>>>(qkv, vT8, sv, cs);
    attn_mfma<true><<<Bz * H * (Ntok / 64), 256, 0, stream>>>(
        q8, k8, vT8, sq, sk, sv, cs, nullptr, ah, am, al);
    gemm3<true><<<dim3(DIMC / 128, Mrows / 128), 256, 0, stream>>>(
        ah, am, al, wph, wpm, wpl, b_proj, out, Mrows, DIMC, DIMC);
  } else {
    // -------- fallback: round-3 fp32-vector-GEMM path --------
    float* aout = (float*)(ws + F_AOUT);
    signed char* q8  = (signed char*)(ws + F_Q8);
    signed char* k8  = (signed char*)(ws + F_K8);
    signed char* vT8 = (signed char*)(ws + F_V8);
    float* sq = (float*)(ws + F_SQ);
    float* sk = (float*)(ws + F_SK);
    float* sv = (float*)(ws + F_SV);
    int*   cs = (int*)(ws + F_CS);
    gemm_bt<false><<<dim3(C3 / 128, Mrows / 128), 256, 0, stream>>>(
        x, w_qkv, nullptr, qkv, Mrows, C3, DIMC);
    quant_qk_pack<<<(Bz * Ntok * 2 * H) / 4, 256, 0, stream>>>(qkv, q8, k8, sq, sk);
    quant_v_pack<<<Bz * H * 80, 256, 0, stream>>>(qkv, vT8, sv, cs);
    attn_mfma<false><<<Bz * H * (Ntok / 64), 256, 0, stream>>>(
        q8, k8, vT8, sq, sk, sv, cs, aout, nullptr, nullptr, nullptr);
    gemm_bt<true><<<dim3(DIMC / 128, Mrows / 128), 256, 0, stream>>>(
        aout, w_proj, b_proj, out, Mrows, DIMC, DIMC);
  }
}

// Round 6
// 723.232 us; speedup vs baseline: 3.4646x; 1.0102x over previous
//
#include <hip/hip_runtime.h>
#include <math.h>

// ---------------------------------------------------------------------------
// QuantizedAttention (round 6): round-5 + latency-hiding attention.
//   attn_mfma changes ONLY:
//     * XCD-aware bijective block swizzle (1024 blocks % 8 == 0): each XCD
//       gets 128 contiguous blocks = 4 whole heads -> per-XCD L2 working set
//       ~2.8 MB < 4 MiB (round-5 FETCH showed 4x refetch without it).
//     * Register double-buffered K-fragment prefetch (kfA/kfB, static index),
//       V-fragments + sk scales issued at body top -> L2 latency hides under
//       QK^T MFMA + softmax VALU. Round-5 counters: VGPR=48, all pipes idle
//       (MfmaUtil 5%, VALUBusy 21%) = serialized-load latency bound.
//   gemm3 / quants / splits / fallback identical to round 5.
// jnp.round == half-even -> rintf. New-path workspace 116.8 MB (aliased).
// ---------------------------------------------------------------------------

typedef int   i32x4  __attribute__((ext_vector_type(4)));
typedef short bf16x8 __attribute__((ext_vector_type(8)));
typedef float f32x4  __attribute__((ext_vector_type(4)));

constexpr int Bz   = 2;
constexpr int Ntok = 2048;
constexpr int DIMC = 1152;
constexpr int H    = 16;
constexpr int HD_  = 72;
constexpr int Mrows = Bz * Ntok;   // 4096
constexpr int C3    = 3 * DIMC;    // 3456

// ---------------- bf16 split helpers ---------------------------------------
__device__ __forceinline__ unsigned short f2bf(float f) {
  unsigned u = __float_as_uint(f);
  return (unsigned short)((u + 0x7fffu + ((u >> 16) & 1u)) >> 16);   // RNE
}
__device__ __forceinline__ float bf2f(unsigned short h) {
  return __uint_as_float((unsigned)h << 16);
}
__device__ __forceinline__ void split1(float v, unsigned short& h,
                                       unsigned short& m, unsigned short& l) {
  h = f2bf(v); float r1 = v - bf2f(h);      // exact
  m = f2bf(r1); float r2 = r1 - bf2f(m);    // exact
  l = f2bf(r2);
}

__global__ __launch_bounds__(256)
void split3_kernel(const float* __restrict__ src, unsigned short* __restrict__ ph,
                   unsigned short* __restrict__ pm, unsigned short* __restrict__ pl,
                   int n4) {
  for (int i = blockIdx.x * 256 + threadIdx.x; i < n4; i += gridDim.x * 256) {
    float4 v = ((const float4*)src)[i];
    ushort4 h, m, l;
    split1(v.x, h.x, m.x, l.x);
    split1(v.y, h.y, m.y, l.y);
    split1(v.z, h.z, m.z, l.z);
    split1(v.w, h.w, m.w, l.w);
    ((ushort4*)ph)[i] = h;
    ((ushort4*)pm)[i] = m;
    ((ushort4*)pl)[i] = l;
  }
}

// ---------------- bf16x3 MFMA GEMM -----------------------------------------
__device__ __forceinline__ void gload16(const void* g, void* l) {
  __builtin_amdgcn_global_load_lds(
      (const __attribute__((address_space(1))) unsigned int*)g,
      (__attribute__((address_space(3))) unsigned int*)l, 16, 0, 0);
}

// C[m][n] = sum_k A(m,k)*W(n,k) (+bias), A/W given as 3 bf16 planes [rows][Kd].
template<bool BIAS>
__global__ __launch_bounds__(256)
void gemm3(const unsigned short* __restrict__ Ah, const unsigned short* __restrict__ Am,
           const unsigned short* __restrict__ Al,
           const unsigned short* __restrict__ Bh, const unsigned short* __restrict__ Bm,
           const unsigned short* __restrict__ Bl,
           const float* __restrict__ bias, float* __restrict__ C,
           int Md, int Nd, int Kd) {
  __shared__ __align__(16) unsigned short As[3][128 * 32];
  __shared__ __align__(16) unsigned short Bs[3][128 * 32];
  const int t = threadIdx.x, lane = t & 63, wv = t >> 6;
  const int r15 = lane & 15, h4 = lane >> 4;
  // XCD-aware bijective block remap (m204 form)
  const int gx = gridDim.x;
  const int nwg = gx * gridDim.y;
  const int orig = blockIdx.y * gx + blockIdx.x;
  const int qq = nwg >> 3, rr = nwg & 7;
  const int xcd = orig & 7, loc = orig >> 3;
  const int wg = (xcd < rr) ? (xcd * (qq + 1) + loc)
                            : (rr * (qq + 1) + (xcd - rr) * qq + loc);
  const int bm = (wg / gx) << 7, bn = (wg % gx) << 7;
  const int wn = (wv & 1) << 6, wm = (wv >> 1) << 6;

  const unsigned short* Ap[3] = {Ah, Am, Al};
  const unsigned short* Bp[3] = {Bh, Bm, Bl};

  f32x4 acc[4][4];
#pragma unroll
  for (int i = 0; i < 4; ++i)
#pragma unroll
    for (int j = 0; j < 4; ++j) acc[i][j] = (f32x4){0.f, 0.f, 0.f, 0.f};

  const int lin0 = t * 16;            // linear LDS byte offset (wave-contiguous)
  const int r0 = lin0 >> 6, cb0 = lin0 & 63;
  const int lin1 = lin0 + 4096;
  const int r1 = lin1 >> 6, cb1 = lin1 & 63;

  for (int k0 = 0; k0 < Kd; k0 += 32) {
    __syncthreads();                  // previous step's compute done
#pragma unroll
    for (int p = 0; p < 3; ++p) {
      gload16((const char*)(Ap[p] + (size_t)(bm + r0) * Kd + k0) + cb0,
              (char*)&As[p][0] + lin0);
      gload16((const char*)(Ap[p] + (size_t)(bm + r1) * Kd + k0) + cb1,
              (char*)&As[p][0] + lin1);
      gload16((const char*)(Bp[p] + (size_t)(bn + r0) * Kd + k0) + cb0,
              (char*)&Bs[p][0] + lin0);
      gload16((const char*)(Bp[p] + (size_t)(bn + r1) * Kd + k0) + cb1,
              (char*)&Bs[p][0] + lin1);
    }
    __syncthreads();                  // drains vmcnt before use
    bf16x8 bf[3][4];
#pragma unroll
    for (int p = 0; p < 3; ++p)
#pragma unroll
      for (int c = 0; c < 4; ++c)
        bf[p][c] = *(const bf16x8*)&Bs[p][(wn + c * 16 + r15) * 32 + h4 * 8];
#pragma unroll
    for (int pa = 0; pa < 3; ++pa) {
#pragma unroll
      for (int mf = 0; mf < 4; ++mf) {
        bf16x8 af = *(const bf16x8*)&As[pa][(wm + mf * 16 + r15) * 32 + h4 * 8];
#pragma unroll
        for (int bp = 0; bp < 3; ++bp) {
          if (bp < 3 - pa) {          // pairs: h*{h,m,l}, m*{h,m}, l*{h}
#pragma unroll
            for (int nf = 0; nf < 4; ++nf)
              acc[mf][nf] = __builtin_amdgcn_mfma_f32_16x16x32_bf16(
                  bf[bp][nf], af, acc[mf][nf], 0, 0, 0);
          }
        }
      }
    }
  }
  // epilogue: D col(lane&15)=m, row((lane>>4)*4+reg)=n -> float4 along n
#pragma unroll
  for (int mf = 0; mf < 4; ++mf) {
    const int m = bm + wm + mf * 16 + r15;
#pragma unroll
    for (int nf = 0; nf < 4; ++nf) {
      const int n = bn + wn + nf * 16 + (h4 << 2);
      float4 o;
      o.x = acc[mf][nf][0]; o.y = acc[mf][nf][1];
      o.z = acc[mf][nf][2]; o.w = acc[mf][nf][3];
      if (BIAS) {
        o.x += bias[n]; o.y += bias[n + 1]; o.z += bias[n + 2]; o.w += bias[n + 3];
      }
      *(float4*)(C + (size_t)m * Nd + n) = o;
    }
  }
}

// ---------------- fp32 vector GEMM (fallback path only) ---------------------
template<bool BIAS>
__global__ __launch_bounds__(256)
void gemm_bt(const float* __restrict__ A, const float* __restrict__ W,
             const float* __restrict__ bias, float* __restrict__ Cout,
             int Md, int Nd, int Kd) {
  __shared__ float As[16][132];
  __shared__ float Bs[16][132];
  const int t  = threadIdx.x;
  const int bm = blockIdx.y << 7, bn = blockIdx.x << 7;
  const int lr = t >> 1;
  const int lk = (t & 1) << 3;
  const float* Ap = A + (size_t)(bm + lr) * Kd + lk;
  const float* Wp = W + (size_t)(bn + lr) * Kd + lk;
  const int tx = t & 15, ty = t >> 4;
  float acc[8][8] = {};
  for (int k0 = 0; k0 < Kd; k0 += 16) {
    float4 a0 = *(const float4*)(Ap + k0);
    float4 a1 = *(const float4*)(Ap + k0 + 4);
    float4 w0 = *(const float4*)(Wp + k0);
    float4 w1 = *(const float4*)(Wp + k0 + 4);
    __syncthreads();
    As[lk + 0][lr] = a0.x; As[lk + 1][lr] = a0.y;
    As[lk + 2][lr] = a0.z; As[lk + 3][lr] = a0.w;
    As[lk + 4][lr] = a1.x; As[lk + 5][lr] = a1.y;
    As[lk + 6][lr] = a1.z; As[lk + 7][lr] = a1.w;
    Bs[lk + 0][lr] = w0.x; Bs[lk + 1][lr] = w0.y;
    Bs[lk + 2][lr] = w0.z; Bs[lk + 3][lr] = w0.w;
    Bs[lk + 4][lr] = w1.x; Bs[lk + 5][lr] = w1.y;
    Bs[lk + 6][lr] = w1.z; Bs[lk + 7][lr] = w1.w;
    __syncthreads();
#pragma unroll
    for (int kk = 0; kk < 16; ++kk) {
      float4 x0 = *(const float4*)&As[kk][(ty << 3) + 0];
      float4 x1 = *(const float4*)&As[kk][(ty << 3) + 4];
      float4 y0 = *(const float4*)&Bs[kk][(tx << 3) + 0];
      float4 y1 = *(const float4*)&Bs[kk][(tx << 3) + 4];
      float ar[8] = {x0.x, x0.y, x0.z, x0.w, x1.x, x1.y, x1.z, x1.w};
      float br[8] = {y0.x, y0.y, y0.z, y0.w, y1.x, y1.y, y1.z, y1.w};
#pragma unroll
      for (int i = 0; i < 8; ++i)
#pragma unroll
        for (int j = 0; j < 8; ++j)
          acc[i][j] = fmaf(ar[i], br[j], acc[i][j]);
    }
  }
  float bias8[8] = {0.f, 0.f, 0.f, 0.f, 0.f, 0.f, 0.f, 0.f};
  if (BIAS) {
#pragma unroll
    for (int j = 0; j < 8; ++j) bias8[j] = bias[bn + (tx << 3) + j];
  }
#pragma unroll
  for (int i = 0; i < 8; ++i) {
    const int m = bm + (ty << 3) + i;
    float* cp = Cout + (size_t)m * Nd + bn + (tx << 3);
    float4 o0, o1;
    o0.x = acc[i][0] + bias8[0]; o0.y = acc[i][1] + bias8[1];
    o0.z = acc[i][2] + bias8[2]; o0.w = acc[i][3] + bias8[3];
    o1.x = acc[i][4] + bias8[4]; o1.y = acc[i][5] + bias8[5];
    o1.z = acc[i][6] + bias8[6]; o1.w = acc[i][7] + bias8[7];
    *(float4*)(cp + 0) = o0;
    *(float4*)(cp + 4) = o1;
  }
}

// --------- quant q,k -> int8 rows (pad 72->128) + scales -------------------
__global__ __launch_bounds__(256)
void quant_qk_pack(const float* __restrict__ qkv,
                   signed char* __restrict__ q8, signed char* __restrict__ k8,
                   float* __restrict__ sq, float* __restrict__ sk) {
  const int wid  = (blockIdx.x << 2) + (threadIdx.x >> 6);  // one wave per row
  const int lane = threadIdx.x & 63;
  const int h  = wid & 15;
  const int g  = (wid >> 4) & 1;        // 0=q, 1=k
  const int bn = wid >> 5;              // 0..4095 = b*2048+n
  const float* row = qkv + (size_t)bn * C3 + g * DIMC + h * HD_;
  float x0 = row[lane];
  float x1 = (lane < 8) ? row[64 + lane] : 0.f;
  float amax = fmaxf(fabsf(x0), fabsf(x1));
#pragma unroll
  for (int s = 32; s; s >>= 1) amax = fmaxf(amax, __shfl_xor(amax, s));
  const float scale = fmaxf(amax, 1e-8f) / 127.f;
  int q0 = (int)fminf(fmaxf(rintf(x0 / scale), -128.f), 127.f);
  int q1 = (int)fminf(fmaxf(rintf(x1 / scale), -128.f), 127.f);
  const int b = bn >> 11, n = bn & 2047;
  signed char* dst = (g ? k8 : q8) + ((size_t)(b * H + h) * Ntok + n) * 128;
  dst[lane] = (signed char)q0;
  dst[64 + lane] = (lane < 8) ? (signed char)q1 : 0;   // zero-pad 72..127
  if (lane == 0) (g ? sk : sq)[(size_t)(b * H + h) * Ntok + n] = scale;
}

// --------- quant v -> int8 transposed [B,H,80,2048] + scale + colsum -------
__global__ __launch_bounds__(256)
void quant_v_pack(const float* __restrict__ qkv, signed char* __restrict__ vT8,
                  float* __restrict__ sv, int* __restrict__ cs) {
  const int col = blockIdx.x;           // 0..2559
  const int d = col % 80;
  const int h = (col / 80) % H;
  const int b = col / (80 * H);
  const int idx = (b * H + h) * 80 + d;
  signed char* vrow = vT8 + (size_t)idx * 2048;
  const int t = threadIdx.x;
  if (d >= HD_) {                       // zero pad rows 72..79
#pragma unroll
    for (int i = 0; i < 8; ++i) vrow[t + (i << 8)] = 0;
    if (t == 0) { sv[idx] = 0.f; cs[idx] = 0; }
    return;
  }
  const float* base = qkv + (size_t)b * Ntok * C3 + 2 * DIMC + h * HD_ + d;
  float vals[8];
  float amax = 0.f;
#pragma unroll
  for (int i = 0; i < 8; ++i) {
    float v = base[(size_t)(t + (i << 8)) * C3];
    vals[i] = v;
    amax = fmaxf(amax, fabsf(v));
  }
#pragma unroll
  for (int s = 32; s; s >>= 1) amax = fmaxf(amax, __shfl_xor(amax, s));
  __shared__ float red[4];
  if ((t & 63) == 0) red[t >> 6] = amax;
  __syncthreads();
  amax = fmaxf(fmaxf(red[0], red[1]), fmaxf(red[2], red[3]));
  const float scale = fmaxf(amax, 1e-8f) / 127.f;
  int isum = 0;
#pragma unroll
  for (int i = 0; i < 8; ++i) {
    int q = (int)fminf(fmaxf(rintf(vals[i] / scale), -128.f), 127.f);
    vrow[t + (i << 8)] = (signed char)q;
    isum += q;
  }
#pragma unroll
  for (int s = 32; s; s >>= 1) isum += __shfl_xor(isum, s);
  __shared__ int ired[4];
  if ((t & 63) == 0) ired[t >> 6] = isum;
  __syncthreads();
  if (t == 0) {
    cs[idx] = ired[0] + ired[1] + ired[2] + ired[3];
    sv[idx] = scale;
  }
}

// --------- int8-MFMA fused attention (latency-hiding version) --------------
__device__ __forceinline__ float logitv(float cl, float skj, int a) {
  return cl * skj * (float)a;   // exact cvt (|a|<2^24); identical in both passes
}

// load the 8 K fragments of key-tile KT into KF (per-lane: row g*16+i16,
// cols h4*16..+15 and +64; kp already offset by h4*16)
#define LOADK(KF, KT)                                                       \
  {                                                                         \
    const signed char* krb_ = kp + (size_t)((KT) * 64 + i16) * 128;         \
    _Pragma("unroll")                                                       \
    for (int g_ = 0; g_ < 4; ++g_) {                                        \
      KF[2 * g_]     = *(const i32x4*)(krb_ + g_ * 2048);                   \
      KF[2 * g_ + 1] = *(const i32x4*)(krb_ + g_ * 2048 + 64);              \
    }                                                                       \
  }

#define BODYA(KT, KF)                                                       \
  {                                                                         \
    float4 skq_[4];                                                         \
    _Pragma("unroll")                                                       \
    for (int g_ = 0; g_ < 4; ++g_)                                          \
      skq_[g_] = *(const float4*)(skp + (KT) * 64 + g_ * 16 + (h4 << 2));   \
    _Pragma("unroll")                                                       \
    for (int g_ = 0; g_ < 4; ++g_) {                                        \
      i32x4 acc_ = {0, 0, 0, 0};                                            \
      acc_ = __builtin_amdgcn_mfma_i32_16x16x64_i8(KF[2*g_],   qf0, acc_, 0, 0, 0); \
      acc_ = __builtin_amdgcn_mfma_i32_16x16x64_i8(KF[2*g_+1], qf1, acc_, 0, 0, 0); \
      mrow = fmaxf(mrow, logitv(cl, skq_[g_].x, acc_[0]));                  \
      mrow = fmaxf(mrow, logitv(cl, skq_[g_].y, acc_[1]));                  \
      mrow = fmaxf(mrow, logitv(cl, skq_[g_].z, acc_[2]));                  \
      mrow = fmaxf(mrow, logitv(cl, skq_[g_].w, acc_[3]));                  \
    }                                                                       \
  }

#define BODYB(KT, KF)                                                       \
  {                                                                         \
    i32x4 vf_[5];                                                           \
    _Pragma("unroll")                                                       \
    for (int dg_ = 0; dg_ < 5; ++dg_)                                       \
      vf_[dg_] = *(const i32x4*)(vp + (size_t)(dg_ * 16 + i16) * 2048 + (KT) * 64); \
    float4 skq_[4];                                                         \
    _Pragma("unroll")                                                       \
    for (int g_ = 0; g_ < 4; ++g_)                                          \
      skq_[g_] = *(const float4*)(skp + (KT) * 64 + g_ * 16 + (h4 << 2));   \
    _Pragma("unroll")                                                       \
    for (int g_ = 0; g_ < 4; ++g_) {                                        \
      i32x4 acc_ = {0, 0, 0, 0};                                            \
      acc_ = __builtin_amdgcn_mfma_i32_16x16x64_i8(KF[2*g_],   qf0, acc_, 0, 0, 0); \
      acc_ = __builtin_amdgcn_mfma_i32_16x16x64_i8(KF[2*g_+1], qf1, acc_, 0, 0, 0); \
      float sks_[4] = {skq_[g_].x, skq_[g_].y, skq_[g_].z, skq_[g_].w};     \
      int packed_ = 0;                                                      \
      _Pragma("unroll")                                                     \
      for (int r_ = 0; r_ < 4; ++r_) {                                      \
        const float lv_ = logitv(cl, sks_[r_], acc_[r_]);                   \
        const float e_ = __expf(lv_ - mrow);                                \
        zacc += e_;                                                         \
        const float u_ = fminf(rintf(e_ * 255.f), 255.f);                   \
        const int s8_ = (int)u_ - 128;                                      \
        packed_ |= (s8_ & 255) << (r_ << 3);                                \
      }                                                                     \
      *(int*)&P[wv][(i16 << 6) + ((g_ ^ sI) << 4) + (h4 << 2)] = packed_;   \
    }                                                                       \
    const i32x4 pf_ = *(const i32x4*)&P[wv][(i16 << 6) + ((h4 ^ sI) << 4)]; \
    _Pragma("unroll")                                                       \
    for (int dg_ = 0; dg_ < 5; ++dg_)                                       \
      pv[dg_] = __builtin_amdgcn_mfma_i32_16x16x64_i8(vf_[dg_], pf_, pv[dg_], 0, 0, 0); \
  }

template<bool SPLIT>
__global__ __launch_bounds__(256)
void attn_mfma(const signed char* __restrict__ q8, const signed char* __restrict__ k8,
               const signed char* __restrict__ vT8,
               const float* __restrict__ sq, const float* __restrict__ sk,
               const float* __restrict__ sv, const int* __restrict__ cs,
               float* __restrict__ aoutF,
               unsigned short* __restrict__ ah, unsigned short* __restrict__ am,
               unsigned short* __restrict__ al) {
  // XCD-aware swizzle: 1024 blocks, 8 XCDs -> 128 contiguous blocks per XCD
  // (= 4 whole heads per XCD; per-XCD L2 working set ~2.8 MB < 4 MiB)
  const int bid = ((blockIdx.x & 7) << 7) + (blockIdx.x >> 3);
  const int qt = bid & 31, h = (bid >> 5) & 15, b = bid >> 9;
  const int n0 = qt << 6;
  const int t = threadIdx.x, lane = t & 63, wv = t >> 6;
  const int i16 = lane & 15, h4 = lane >> 4;
  const int bh = b * H + h;
  const int sI = (i16 >> 1) & 3;        // XOR-swizzle key (2-way banks = free)

  __shared__ __align__(16) signed char P[4][1024];   // per-wave 16 rows x 64 keys

  // Q fragments (B-operand): lane holds q8[row i16][d = h4*16.. (+c*64)]
  const int qrow = n0 + (wv << 4) + i16;
  const signed char* qp = q8 + ((size_t)bh * Ntok + qrow) * 128 + (h4 << 4);
  const i32x4 qf0 = *(const i32x4*)qp;
  const i32x4 qf1 = *(const i32x4*)(qp + 64);
  const float cl = sq[(size_t)bh * Ntok + qrow] * 0.11785113019775793f;
  const float* skp = sk + (size_t)bh * Ntok;
  const signed char* kp = k8 + (size_t)bh * Ntok * 128 + (h4 << 4);
  const signed char* vp = vT8 + (size_t)bh * 80 * 2048 + (h4 << 4);

  i32x4 kfA[8], kfB[8];

  // ---------------- pass A: global row max ----------------
  float mrow = -3.4e38f;
  LOADK(kfA, 0);
  for (int kt = 0; kt < 32; kt += 2) {
    LOADK(kfB, kt + 1);               // prefetch odd tile
    BODYA(kt, kfA);
    if (kt < 30) LOADK(kfA, kt + 2);  // prefetch next even tile
    BODYA(kt + 1, kfB);
  }
  mrow = fmaxf(mrow, __shfl_xor(mrow, 16));
  mrow = fmaxf(mrow, __shfl_xor(mrow, 32));

  // ---------------- pass B: exp/round + PV ----------------
  float zacc = 0.f;
  i32x4 pv[5];
#pragma unroll
  for (int dg = 0; dg < 5; ++dg) pv[dg] = (i32x4){0, 0, 0, 0};

  LOADK(kfA, 0);
  for (int kt = 0; kt < 32; kt += 2) {
    LOADK(kfB, kt + 1);
    BODYB(kt, kfA);
    if (kt < 30) LOADK(kfA, kt + 2);
    BODYB(kt + 1, kfB);
  }

  // ---------------- epilogue ----------------
  float z = zacc;
  z += __shfl_xor(z, 16);
  z += __shfl_xor(z, 32);
  const float rz = 1.0f / z;
  const float ss = rz / 255.f;

  const size_t rowoff = ((size_t)(b * Ntok + n0 + (wv << 4) + i16)) * DIMC + h * HD_;
  const int sbase = bh * 80;
#pragma unroll
  for (int dg = 0; dg < 5; ++dg) {
    const int d0 = dg * 16 + (h4 << 2);
    if (d0 < HD_) {
      float4 o;
      int t0 = pv[dg][0] + (cs[sbase + d0 + 0] << 7);
      int t1 = pv[dg][1] + (cs[sbase + d0 + 1] << 7);
      int t2 = pv[dg][2] + (cs[sbase + d0 + 2] << 7);
      int t3 = pv[dg][3] + (cs[sbase + d0 + 3] << 7);
      o.x = (float)t0 * sv[sbase + d0 + 0] * ss;
      o.y = (float)t1 * sv[sbase + d0 + 1] * ss;
      o.z = (float)t2 * sv[sbase + d0 + 2] * ss;
      o.w = (float)t3 * sv[sbase + d0 + 3] * ss;
      if (SPLIT) {
        ushort4 hh, mm, ll;
        split1(o.x, hh.x, mm.x, ll.x);
        split1(o.y, hh.y, mm.y, ll.y);
        split1(o.z, hh.z, mm.z, ll.z);
        split1(o.w, hh.w, mm.w, ll.w);
        *(ushort4*)(ah + rowoff + d0) = hh;
        *(ushort4*)(am + rowoff + d0) = mm;
        *(ushort4*)(al + rowoff + d0) = ll;
      } else {
        *(float4*)(aoutF + rowoff + d0) = o;
      }
    }
  }
}

// ---------------------------------------------------------------------------
// New-path workspace layout (aliased):
constexpr size_t SZ_QKV  = (size_t)Mrows * C3 * 4;        // 56,623,104
constexpr size_t PL_X    = (size_t)Mrows * DIMC * 2;      //  9,437,184 (x/a plane)
constexpr size_t PL_WQ   = (size_t)C3 * DIMC * 2;         //  7,962,624
constexpr size_t PL_WP   = (size_t)DIMC * DIMC * 2;       //  2,654,208
constexpr size_t OFF_XA  = SZ_QKV;                        // x-planes, later a-planes
constexpr size_t OFF_WQ  = OFF_XA + 3 * PL_X;             // wq-planes, later int8 bufs
constexpr size_t OFF_WP  = OFF_WQ + 3 * PL_WQ;
constexpr size_t REQ_NEW = OFF_WP + 3 * PL_WP;            // 116,785,152
// int8/scale aliases inside WQ region (WQ dead after qkv-gemm):
constexpr size_t SZ_Q8 = (size_t)Bz * H * Ntok * 128;     // 8,388,608
constexpr size_t SZ_V8 = (size_t)Bz * H * 80 * 2048;      // 5,242,880
constexpr size_t SZ_S  = (size_t)Bz * H * Ntok * 4;       //   524,288
constexpr size_t SZ_SV = (size_t)Bz * H * 80 * 4;         //    10,240
constexpr size_t A_Q8 = OFF_WQ;
constexpr size_t A_K8 = A_Q8 + SZ_Q8;
constexpr size_t A_V8 = A_K8 + SZ_Q8;
constexpr size_t A_SQ = A_V8 + SZ_V8;
constexpr size_t A_SK = A_SQ + SZ_S;
constexpr size_t A_SV = A_SK + SZ_S;
constexpr size_t A_CS = A_SV + SZ_SV;
static_assert(A_CS + SZ_SV <= OFF_WP, "alias overflow");
// Fallback (round-3) layout:
constexpr size_t F_AOUT = SZ_QKV;
constexpr size_t F_Q8   = F_AOUT + (size_t)Mrows * DIMC * 4;
constexpr size_t F_K8   = F_Q8 + SZ_Q8;
constexpr size_t F_V8   = F_K8 + SZ_Q8;
constexpr size_t F_SQ   = F_V8 + SZ_V8;
constexpr size_t F_SK   = F_SQ + SZ_S;
constexpr size_t F_SV   = F_SK + SZ_S;
constexpr size_t F_CS   = F_SV + SZ_SV;

extern "C" void kernel_launch(void* const* d_in, const int* in_sizes, int n_in,
                              void* d_out, int out_size, void* d_ws, size_t ws_size,
                              hipStream_t stream) {
  const float* x      = (const float*)d_in[0];
  const float* w_qkv  = (const float*)d_in[1];
  const float* w_proj = (const float*)d_in[2];
  const float* b_proj = (const float*)d_in[3];
  float* out = (float*)d_out;
  char* ws = (char*)d_ws;
  float* qkv = (float*)ws;

  if (ws_size >= REQ_NEW) {
    unsigned short* xh = (unsigned short*)(ws + OFF_XA);
    unsigned short* xm = xh + PL_X / 2;
    unsigned short* xl = xm + PL_X / 2;
    unsigned short* wqh = (unsigned short*)(ws + OFF_WQ);
    unsigned short* wqm = wqh + PL_WQ / 2;
    unsigned short* wql = wqm + PL_WQ / 2;
    unsigned short* wph = (unsigned short*)(ws + OFF_WP);
    unsigned short* wpm = wph + PL_WP / 2;
    unsigned short* wpl = wpm + PL_WP / 2;
    signed char* q8  = (signed char*)(ws + A_Q8);
    signed char* k8  = (signed char*)(ws + A_K8);
    signed char* vT8 = (signed char*)(ws + A_V8);
    float* sq = (float*)(ws + A_SQ);
    float* sk = (float*)(ws + A_SK);
    float* sv = (float*)(ws + A_SV);
    int*   cs = (int*)(ws + A_CS);
    // a-planes alias x-planes (x dead after qkv-gemm; attn writes them)
    unsigned short* ah = xh;
    unsigned short* am = xm;
    unsigned short* al = xl;

    split3_kernel<<<2048, 256, 0, stream>>>(x, xh, xm, xl, Mrows * DIMC / 4);
    split3_kernel<<<2048, 256, 0, stream>>>(w_qkv, wqh, wqm, wql, C3 * DIMC / 4);
    split3_kernel<<<1297, 256, 0, stream>>>(w_proj, wph, wpm, wpl, DIMC * DIMC / 4);
    gemm3<false><<<dim3(C3 / 128, Mrows / 128), 256, 0, stream>>>(
        xh, xm, xl, wqh, wqm, wql, nullptr, qkv, Mrows, C3, DIMC);
    quant_qk_pack<<<(Bz * Ntok * 2 * H) / 4, 256, 0, stream>>>(qkv, q8, k8, sq, sk);
    quant_v_pack<<<Bz * H * 80, 256, 0, stream>>>(qkv, vT8, sv, cs);
    attn_mfma<true><<<Bz * H * (Ntok / 64), 256, 0, stream>>>(
        q8, k8, vT8, sq, sk, sv, cs, nullptr, ah, am, al);
    gemm3<true><<<dim3(DIMC / 128, Mrows / 128), 256, 0, stream>>>(
        ah, am, al, wph, wpm, wpl, b_proj, out, Mrows, DIMC, DIMC);
  } else {
    // -------- fallback: round-3 fp32-vector-GEMM path --------
    float* aout = (float*)(ws + F_AOUT);
    signed char* q8  = (signed char*)(ws + F_Q8);
    signed char* k8  = (signed char*)(ws + F_K8);
    signed char* vT8 = (signed char*)(ws + F_V8);
    float* sq = (float*)(ws + F_SQ);
    float* sk = (float*)(ws + F_SK);
    float* sv = (float*)(ws + F_SV);
    int*   cs = (int*)(ws + F_CS);
    gemm_bt<false><<<dim3(C3 / 128, Mrows / 128), 256, 0, stream>>>(
        x, w_qkv, nullptr, qkv, Mrows, C3, DIMC);
    quant_qk_pack<<<(Bz * Ntok * 2 * H) / 4, 256, 0, stream>>>(qkv, q8, k8, sq, sk);
    quant_v_pack<<<Bz * H * 80, 256, 0, stream>>>(qkv, vT8, sv, cs);
    attn_mfma<false><<<Bz * H * (Ntok / 64), 256, 0, stream>>>(
        q8, k8, vT8, sq, sk, sv, cs, aout, nullptr, nullptr, nullptr);
    gemm_bt<true><<<dim3(DIMC / 128, Mrows / 128), 256, 0, stream>>>(
        aout, w_proj, b_proj, out, Mrows, DIMC, DIMC);
  }
}

// Round 7
// 504.056 us; speedup vs baseline: 4.9711x; 1.4348x over previous
//
#include <hip/hip_runtime.h>
#include <math.h>

// ---------------------------------------------------------------------------
// QuantizedAttention (round 7): LDS-staged int8-MFMA attention (m97 structure).
//   Round-6 lesson: register-level K prefetch was defeated by the register
//   allocator (VGPR=100, all pipes idle, same 347us). Fix: the block's 4 waves
//   share all K/V tiles -> stage per-block via async global_load_lds
//   (zero VGPR, vmcnt-counted), 2-barrier loop per tile. XOR swizzles applied
//   on the GLOBAL source address (linear LDS dest) + same XOR on ds_read:
//     K[64][128]: col ^ ((row&7)<<4)   V[80][64]: col ^ ((row&3)<<4)
//   Serial zacc/mrow chains split into 4 accumulators.
//   gemm3 / quants / splits / fallback identical to round 5/6.
// jnp.round == half-even -> rintf. New-path workspace 116.8 MB (aliased).
// ---------------------------------------------------------------------------

typedef int   i32x4  __attribute__((ext_vector_type(4)));
typedef short bf16x8 __attribute__((ext_vector_type(8)));
typedef float f32x4  __attribute__((ext_vector_type(4)));

constexpr int Bz   = 2;
constexpr int Ntok = 2048;
constexpr int DIMC = 1152;
constexpr int H    = 16;
constexpr int HD_  = 72;
constexpr int Mrows = Bz * Ntok;   // 4096
constexpr int C3    = 3 * DIMC;    // 3456

// ---------------- bf16 split helpers ---------------------------------------
__device__ __forceinline__ unsigned short f2bf(float f) {
  unsigned u = __float_as_uint(f);
  return (unsigned short)((u + 0x7fffu + ((u >> 16) & 1u)) >> 16);   // RNE
}
__device__ __forceinline__ float bf2f(unsigned short h) {
  return __uint_as_float((unsigned)h << 16);
}
__device__ __forceinline__ void split1(float v, unsigned short& h,
                                       unsigned short& m, unsigned short& l) {
  h = f2bf(v); float r1 = v - bf2f(h);      // exact
  m = f2bf(r1); float r2 = r1 - bf2f(m);    // exact
  l = f2bf(r2);
}

__global__ __launch_bounds__(256)
void split3_kernel(const float* __restrict__ src, unsigned short* __restrict__ ph,
                   unsigned short* __restrict__ pm, unsigned short* __restrict__ pl,
                   int n4) {
  for (int i = blockIdx.x * 256 + threadIdx.x; i < n4; i += gridDim.x * 256) {
    float4 v = ((const float4*)src)[i];
    ushort4 h, m, l;
    split1(v.x, h.x, m.x, l.x);
    split1(v.y, h.y, m.y, l.y);
    split1(v.z, h.z, m.z, l.z);
    split1(v.w, h.w, m.w, l.w);
    ((ushort4*)ph)[i] = h;
    ((ushort4*)pm)[i] = m;
    ((ushort4*)pl)[i] = l;
  }
}

// ---------------- async global->LDS ----------------------------------------
__device__ __forceinline__ void gload16(const void* g, void* l) {
  __builtin_amdgcn_global_load_lds(
      (const __attribute__((address_space(1))) unsigned int*)g,
      (__attribute__((address_space(3))) unsigned int*)l, 16, 0, 0);
}

// ---------------- bf16x3 MFMA GEMM -----------------------------------------
// C[m][n] = sum_k A(m,k)*W(n,k) (+bias), A/W given as 3 bf16 planes [rows][Kd].
template<bool BIAS>
__global__ __launch_bounds__(256)
void gemm3(const unsigned short* __restrict__ Ah, const unsigned short* __restrict__ Am,
           const unsigned short* __restrict__ Al,
           const unsigned short* __restrict__ Bh, const unsigned short* __restrict__ Bm,
           const unsigned short* __restrict__ Bl,
           const float* __restrict__ bias, float* __restrict__ C,
           int Md, int Nd, int Kd) {
  __shared__ __align__(16) unsigned short As[3][128 * 32];
  __shared__ __align__(16) unsigned short Bs[3][128 * 32];
  const int t = threadIdx.x, lane = t & 63, wv = t >> 6;
  const int r15 = lane & 15, h4 = lane >> 4;
  // XCD-aware bijective block remap (m204 form)
  const int gx = gridDim.x;
  const int nwg = gx * gridDim.y;
  const int orig = blockIdx.y * gx + blockIdx.x;
  const int qq = nwg >> 3, rr = nwg & 7;
  const int xcd = orig & 7, loc = orig >> 3;
  const int wg = (xcd < rr) ? (xcd * (qq + 1) + loc)
                            : (rr * (qq + 1) + (xcd - rr) * qq + loc);
  const int bm = (wg / gx) << 7, bn = (wg % gx) << 7;
  const int wn = (wv & 1) << 6, wm = (wv >> 1) << 6;

  const unsigned short* Ap[3] = {Ah, Am, Al};
  const unsigned short* Bp[3] = {Bh, Bm, Bl};

  f32x4 acc[4][4];
#pragma unroll
  for (int i = 0; i < 4; ++i)
#pragma unroll
    for (int j = 0; j < 4; ++j) acc[i][j] = (f32x4){0.f, 0.f, 0.f, 0.f};

  const int lin0 = t * 16;            // linear LDS byte offset (wave-contiguous)
  const int r0 = lin0 >> 6, cb0 = lin0 & 63;
  const int lin1 = lin0 + 4096;
  const int r1 = lin1 >> 6, cb1 = lin1 & 63;

  for (int k0 = 0; k0 < Kd; k0 += 32) {
    __syncthreads();                  // previous step's compute done
#pragma unroll
    for (int p = 0; p < 3; ++p) {
      gload16((const char*)(Ap[p] + (size_t)(bm + r0) * Kd + k0) + cb0,
              (char*)&As[p][0] + lin0);
      gload16((const char*)(Ap[p] + (size_t)(bm + r1) * Kd + k0) + cb1,
              (char*)&As[p][0] + lin1);
      gload16((const char*)(Bp[p] + (size_t)(bn + r0) * Kd + k0) + cb0,
              (char*)&Bs[p][0] + lin0);
      gload16((const char*)(Bp[p] + (size_t)(bn + r1) * Kd + k0) + cb1,
              (char*)&Bs[p][0] + lin1);
    }
    __syncthreads();                  // drains vmcnt before use
    bf16x8 bf[3][4];
#pragma unroll
    for (int p = 0; p < 3; ++p)
#pragma unroll
      for (int c = 0; c < 4; ++c)
        bf[p][c] = *(const bf16x8*)&Bs[p][(wn + c * 16 + r15) * 32 + h4 * 8];
#pragma unroll
    for (int pa = 0; pa < 3; ++pa) {
#pragma unroll
      for (int mf = 0; mf < 4; ++mf) {
        bf16x8 af = *(const bf16x8*)&As[pa][(wm + mf * 16 + r15) * 32 + h4 * 8];
#pragma unroll
        for (int bp = 0; bp < 3; ++bp) {
          if (bp < 3 - pa) {          // pairs: h*{h,m,l}, m*{h,m}, l*{h}
#pragma unroll
            for (int nf = 0; nf < 4; ++nf)
              acc[mf][nf] = __builtin_amdgcn_mfma_f32_16x16x32_bf16(
                  bf[bp][nf], af, acc[mf][nf], 0, 0, 0);
          }
        }
      }
    }
  }
  // epilogue: D col(lane&15)=m, row((lane>>4)*4+reg)=n -> float4 along n
#pragma unroll
  for (int mf = 0; mf < 4; ++mf) {
    const int m = bm + wm + mf * 16 + r15;
#pragma unroll
    for (int nf = 0; nf < 4; ++nf) {
      const int n = bn + wn + nf * 16 + (h4 << 2);
      float4 o;
      o.x = acc[mf][nf][0]; o.y = acc[mf][nf][1];
      o.z = acc[mf][nf][2]; o.w = acc[mf][nf][3];
      if (BIAS) {
        o.x += bias[n]; o.y += bias[n + 1]; o.z += bias[n + 2]; o.w += bias[n + 3];
      }
      *(float4*)(C + (size_t)m * Nd + n) = o;
    }
  }
}

// ---------------- fp32 vector GEMM (fallback path only) ---------------------
template<bool BIAS>
__global__ __launch_bounds__(256)
void gemm_bt(const float* __restrict__ A, const float* __restrict__ W,
             const float* __restrict__ bias, float* __restrict__ Cout,
             int Md, int Nd, int Kd) {
  __shared__ float As[16][132];
  __shared__ float Bs[16][132];
  const int t  = threadIdx.x;
  const int bm = blockIdx.y << 7, bn = blockIdx.x << 7;
  const int lr = t >> 1;
  const int lk = (t & 1) << 3;
  const float* Ap = A + (size_t)(bm + lr) * Kd + lk;
  const float* Wp = W + (size_t)(bn + lr) * Kd + lk;
  const int tx = t & 15, ty = t >> 4;
  float acc[8][8] = {};
  for (int k0 = 0; k0 < Kd; k0 += 16) {
    float4 a0 = *(const float4*)(Ap + k0);
    float4 a1 = *(const float4*)(Ap + k0 + 4);
    float4 w0 = *(const float4*)(Wp + k0);
    float4 w1 = *(const float4*)(Wp + k0 + 4);
    __syncthreads();
    As[lk + 0][lr] = a0.x; As[lk + 1][lr] = a0.y;
    As[lk + 2][lr] = a0.z; As[lk + 3][lr] = a0.w;
    As[lk + 4][lr] = a1.x; As[lk + 5][lr] = a1.y;
    As[lk + 6][lr] = a1.z; As[lk + 7][lr] = a1.w;
    Bs[lk + 0][lr] = w0.x; Bs[lk + 1][lr] = w0.y;
    Bs[lk + 2][lr] = w0.z; Bs[lk + 3][lr] = w0.w;
    Bs[lk + 4][lr] = w1.x; Bs[lk + 5][lr] = w1.y;
    Bs[lk + 6][lr] = w1.z; Bs[lk + 7][lr] = w1.w;
    __syncthreads();
#pragma unroll
    for (int kk = 0; kk < 16; ++kk) {
      float4 x0 = *(const float4*)&As[kk][(ty << 3) + 0];
      float4 x1 = *(const float4*)&As[kk][(ty << 3) + 4];
      float4 y0 = *(const float4*)&Bs[kk][(tx << 3) + 0];
      float4 y1 = *(const float4*)&Bs[kk][(tx << 3) + 4];
      float ar[8] = {x0.x, x0.y, x0.z, x0.w, x1.x, x1.y, x1.z, x1.w};
      float br[8] = {y0.x, y0.y, y0.z, y0.w, y1.x, y1.y, y1.z, y1.w};
#pragma unroll
      for (int i = 0; i < 8; ++i)
#pragma unroll
        for (int j = 0; j < 8; ++j)
          acc[i][j] = fmaf(ar[i], br[j], acc[i][j]);
    }
  }
  float bias8[8] = {0.f, 0.f, 0.f, 0.f, 0.f, 0.f, 0.f, 0.f};
  if (BIAS) {
#pragma unroll
    for (int j = 0; j < 8; ++j) bias8[j] = bias[bn + (tx << 3) + j];
  }
#pragma unroll
  for (int i = 0; i < 8; ++i) {
    const int m = bm + (ty << 3) + i;
    float* cp = Cout + (size_t)m * Nd + bn + (tx << 3);
    float4 o0, o1;
    o0.x = acc[i][0] + bias8[0]; o0.y = acc[i][1] + bias8[1];
    o0.z = acc[i][2] + bias8[2]; o0.w = acc[i][3] + bias8[3];
    o1.x = acc[i][4] + bias8[4]; o1.y = acc[i][5] + bias8[5];
    o1.z = acc[i][6] + bias8[6]; o1.w = acc[i][7] + bias8[7];
    *(float4*)(cp + 0) = o0;
    *(float4*)(cp + 4) = o1;
  }
}

// --------- quant q,k -> int8 rows (pad 72->128) + scales -------------------
__global__ __launch_bounds__(256)
void quant_qk_pack(const float* __restrict__ qkv,
                   signed char* __restrict__ q8, signed char* __restrict__ k8,
                   float* __restrict__ sq, float* __restrict__ sk) {
  const int wid  = (blockIdx.x << 2) + (threadIdx.x >> 6);  // one wave per row
  const int lane = threadIdx.x & 63;
  const int h  = wid & 15;
  const int g  = (wid >> 4) & 1;        // 0=q, 1=k
  const int bn = wid >> 5;              // 0..4095 = b*2048+n
  const float* row = qkv + (size_t)bn * C3 + g * DIMC + h * HD_;
  float x0 = row[lane];
  float x1 = (lane < 8) ? row[64 + lane] : 0.f;
  float amax = fmaxf(fabsf(x0), fabsf(x1));
#pragma unroll
  for (int s = 32; s; s >>= 1) amax = fmaxf(amax, __shfl_xor(amax, s));
  const float scale = fmaxf(amax, 1e-8f) / 127.f;
  int q0 = (int)fminf(fmaxf(rintf(x0 / scale), -128.f), 127.f);
  int q1 = (int)fminf(fmaxf(rintf(x1 / scale), -128.f), 127.f);
  const int b = bn >> 11, n = bn & 2047;
  signed char* dst = (g ? k8 : q8) + ((size_t)(b * H + h) * Ntok + n) * 128;
  dst[lane] = (signed char)q0;
  dst[64 + lane] = (lane < 8) ? (signed char)q1 : 0;   // zero-pad 72..127
  if (lane == 0) (g ? sk : sq)[(size_t)(b * H + h) * Ntok + n] = scale;
}

// --------- quant v -> int8 transposed [B,H,80,2048] + scale + colsum -------
__global__ __launch_bounds__(256)
void quant_v_pack(const float* __restrict__ qkv, signed char* __restrict__ vT8,
                  float* __restrict__ sv, int* __restrict__ cs) {
  const int col = blockIdx.x;           // 0..2559
  const int d = col % 80;
  const int h = (col / 80) % H;
  const int b = col / (80 * H);
  const int idx = (b * H + h) * 80 + d;
  signed char* vrow = vT8 + (size_t)idx * 2048;
  const int t = threadIdx.x;
  if (d >= HD_) {                       // zero pad rows 72..79
#pragma unroll
    for (int i = 0; i < 8; ++i) vrow[t + (i << 8)] = 0;
    if (t == 0) { sv[idx] = 0.f; cs[idx] = 0; }
    return;
  }
  const float* base = qkv + (size_t)b * Ntok * C3 + 2 * DIMC + h * HD_ + d;
  float vals[8];
  float amax = 0.f;
#pragma unroll
  for (int i = 0; i < 8; ++i) {
    float v = base[(size_t)(t + (i << 8)) * C3];
    vals[i] = v;
    amax = fmaxf(amax, fabsf(v));
  }
#pragma unroll
  for (int s = 32; s; s >>= 1) amax = fmaxf(amax, __shfl_xor(amax, s));
  __shared__ float red[4];
  if ((t & 63) == 0) red[t >> 6] = amax;
  __syncthreads();
  amax = fmaxf(fmaxf(red[0], red[1]), fmaxf(red[2], red[3]));
  const float scale = fmaxf(amax, 1e-8f) / 127.f;
  int isum = 0;
#pragma unroll
  for (int i = 0; i < 8; ++i) {
    int q = (int)fminf(fmaxf(rintf(vals[i] / scale), -128.f), 127.f);
    vrow[t + (i << 8)] = (signed char)q;
    isum += q;
  }
#pragma unroll
  for (int s = 32; s; s >>= 1) isum += __shfl_xor(isum, s);
  __shared__ int ired[4];
  if ((t & 63) == 0) ired[t >> 6] = isum;
  __syncthreads();
  if (t == 0) {
    cs[idx] = ired[0] + ired[1] + ired[2] + ired[3];
    sv[idx] = scale;
  }
}

// --------- int8-MFMA fused attention, LDS-staged ---------------------------
__device__ __forceinline__ float logitv(float cl, float skj, int a) {
  return cl * skj * (float)a;   // exact cvt (|a|<2^24); identical in both passes
}

// K tile: 64 keys x 128 B, XOR-swizzled source (col ^ ((row&7)<<4)), linear LDS.
#define STAGE_K(KT)                                                          \
  {                                                                          \
    _Pragma("unroll")                                                        \
    for (int c_ = 0; c_ < 2; ++c_) {                                         \
      const int L_ = (t + (c_ << 8)) << 4;                                   \
      const int row_ = L_ >> 7;                                              \
      const int col_ = L_ & 127;                                             \
      gload16(kgbase + (size_t)(KT) * 8192 + row_ * 128 +                    \
                  (col_ ^ ((row_ & 7) << 4)),                                \
              Ks + L_);                                                      \
    }                                                                        \
  }
// sk tile: 64 floats = 256 B, linear (threads 0..15)
#define STAGE_SK(KT)                                                         \
  if (t < 16) {                                                              \
    gload16(skgbase + (KT) * 256 + (t << 4), (signed char*)Sks + (t << 4));  \
  }
// V tile: 80 rows x 64 B = 5120 B, XOR-swizzled source (col ^ ((row&3)<<4))
#define STAGE_V(KT)                                                          \
  {                                                                          \
    const int L_ = t << 4;                                                   \
    const int row_ = L_ >> 6, col_ = L_ & 63;                                \
    gload16(vgbase + (size_t)row_ * 2048 + (KT) * 64 +                       \
                (col_ ^ ((row_ & 3) << 4)),                                  \
            Vs + L_);                                                        \
    if (t < 64) {                                                            \
      const int L2_ = (t + 256) << 4;                                        \
      const int row2_ = L2_ >> 6, col2_ = L2_ & 63;                          \
      gload16(vgbase + (size_t)row2_ * 2048 + (KT) * 64 +                    \
                  (col2_ ^ ((row2_ & 3) << 4)),                              \
              Vs + L2_);                                                     \
    }                                                                        \
  }

#define BODYA                                                                 \
  {                                                                           \
    _Pragma("unroll")                                                         \
    for (int g_ = 0; g_ < 4; ++g_) {                                          \
      const int krow_ = (g_ << 4) + i16;                                      \
      const int kx_ = (krow_ & 7) << 4;                                       \
      const i32x4 kf0_ = *(const i32x4*)&Ks[krow_ * 128 + ((h4 << 4) ^ kx_)]; \
      const i32x4 kf1_ = *(const i32x4*)&Ks[krow_ * 128 + ((64 | (h4 << 4)) ^ kx_)]; \
      i32x4 acc_ = {0, 0, 0, 0};                                              \
      acc_ = __builtin_amdgcn_mfma_i32_16x16x64_i8(kf0_, qf0, acc_, 0, 0, 0); \
      acc_ = __builtin_amdgcn_mfma_i32_16x16x64_i8(kf1_, qf1, acc_, 0, 0, 0); \
      const float4 skv_ = *(const float4*)&Sks[(g_ << 4) + (h4 << 2)];        \
      mr4[g_] = fmaxf(mr4[g_], logitv(cl, skv_.x, acc_[0]));                  \
      mr4[g_] = fmaxf(mr4[g_], logitv(cl, skv_.y, acc_[1]));                  \
      mr4[g_] = fmaxf(mr4[g_], logitv(cl, skv_.z, acc_[2]));                  \
      mr4[g_] = fmaxf(mr4[g_], logitv(cl, skv_.w, acc_[3]));                  \
    }                                                                         \
  }

#define BODYB                                                                 \
  {                                                                           \
    _Pragma("unroll")                                                         \
    for (int g_ = 0; g_ < 4; ++g_) {                                          \
      const int krow_ = (g_ << 4) + i16;                                      \
      const int kx_ = (krow_ & 7) << 4;                                       \
      const i32x4 kf0_ = *(const i32x4*)&Ks[krow_ * 128 + ((h4 << 4) ^ kx_)]; \
      const i32x4 kf1_ = *(const i32x4*)&Ks[krow_ * 128 + ((64 | (h4 << 4)) ^ kx_)]; \
      i32x4 acc_ = {0, 0, 0, 0};                                              \
      acc_ = __builtin_amdgcn_mfma_i32_16x16x64_i8(kf0_, qf0, acc_, 0, 0, 0); \
      acc_ = __builtin_amdgcn_mfma_i32_16x16x64_i8(kf1_, qf1, acc_, 0, 0, 0); \
      const float4 skv_ = *(const float4*)&Sks[(g_ << 4) + (h4 << 2)];        \
      const float sks_[4] = {skv_.x, skv_.y, skv_.z, skv_.w};                 \
      int packed_ = 0;                                                        \
      _Pragma("unroll")                                                       \
      for (int r_ = 0; r_ < 4; ++r_) {                                        \
        const float lv_ = logitv(cl, sks_[r_], acc_[r_]);                     \
        const float e_ = __expf(lv_ - mrow);   /* lv<=mrow bitwise */         \
        z4[g_] += e_;                                                         \
        const float u_ = fminf(rintf(e_ * 255.f), 255.f);                     \
        const int s8_ = (int)u_ - 128;                                        \
        packed_ |= (s8_ & 255) << (r_ << 3);                                  \
      }                                                                       \
      *(int*)&P[wv][(i16 << 6) + ((g_ ^ sI) << 4) + (h4 << 2)] = packed_;     \
    }                                                                         \
    const i32x4 pf_ = *(const i32x4*)&P[wv][(i16 << 6) + ((h4 ^ sI) << 4)];   \
    _Pragma("unroll")                                                         \
    for (int dg_ = 0; dg_ < 5; ++dg_) {                                       \
      const int vrow_ = (dg_ << 4) + i16;                                     \
      const int vx_ = (vrow_ & 3) << 4;                                       \
      const i32x4 vf_ = *(const i32x4*)&Vs[vrow_ * 64 + ((h4 << 4) ^ vx_)];   \
      pv[dg_] = __builtin_amdgcn_mfma_i32_16x16x64_i8(vf_, pf_, pv[dg_], 0, 0, 0); \
    }                                                                         \
  }

template<bool SPLIT>
__global__ __launch_bounds__(256)
void attn_mfma(const signed char* __restrict__ q8, const signed char* __restrict__ k8,
               const signed char* __restrict__ vT8,
               const float* __restrict__ sq, const float* __restrict__ sk,
               const float* __restrict__ sv, const int* __restrict__ cs,
               float* __restrict__ aoutF,
               unsigned short* __restrict__ ah, unsigned short* __restrict__ am,
               unsigned short* __restrict__ al) {
  // XCD swizzle: contiguous 128-block chunks per XCD (kept: FETCH 92->11MB)
  const int bid = ((blockIdx.x & 7) << 7) + (blockIdx.x >> 3);
  const int qt = bid & 31, h = (bid >> 5) & 15, b = bid >> 9;
  const int n0 = qt << 6;
  const int t = threadIdx.x, lane = t & 63, wv = t >> 6;
  const int i16 = lane & 15, h4 = lane >> 4;
  const int bh = b * H + h;
  const int sI = (i16 >> 1) & 3;        // P-tile XOR-swizzle key

  __shared__ __align__(16) signed char Ks[8192];    // 64 keys x 128 B (swz)
  __shared__ __align__(16) signed char Vs[5120];    // 80 d x 64 B (swz)
  __shared__ __align__(16) float Sks[64];           // k scales of tile
  __shared__ __align__(16) signed char P[4][1024];  // per-wave 16 x 64 u-bytes

  // Q fragments (B-operand): lane holds q8[row i16][d = h4*16.. (+64)]
  const int qrow = n0 + (wv << 4) + i16;
  const signed char* qp = q8 + ((size_t)bh * Ntok + qrow) * 128 + (h4 << 4);
  const i32x4 qf0 = *(const i32x4*)qp;
  const i32x4 qf1 = *(const i32x4*)(qp + 64);
  const float cl = sq[(size_t)bh * Ntok + qrow] * 0.11785113019775793f;
  const signed char* kgbase  = k8 + (size_t)bh * Ntok * 128;
  const signed char* vgbase  = vT8 + (size_t)bh * 80 * 2048;
  const signed char* skgbase = (const signed char*)(sk + (size_t)bh * Ntok);

  // ---------------- pass A: global row max ----------------
  float mr4[4];
#pragma unroll
  for (int g = 0; g < 4; ++g) mr4[g] = -3.4e38f;
  for (int kt = 0; kt < 32; ++kt) {
    __syncthreads();                  // all waves done with previous tile
    STAGE_K(kt);
    STAGE_SK(kt);
    __syncthreads();                  // vmcnt drained by barrier
    BODYA;
  }
  float mrow = fmaxf(fmaxf(mr4[0], mr4[1]), fmaxf(mr4[2], mr4[3]));
  mrow = fmaxf(mrow, __shfl_xor(mrow, 16));
  mrow = fmaxf(mrow, __shfl_xor(mrow, 32));

  // ---------------- pass B: exp/round + PV ----------------
  float z4[4] = {0.f, 0.f, 0.f, 0.f};
  i32x4 pv[5];
#pragma unroll
  for (int dg = 0; dg < 5; ++dg) pv[dg] = (i32x4){0, 0, 0, 0};

  for (int kt = 0; kt < 32; ++kt) {
    __syncthreads();
    STAGE_K(kt);
    STAGE_V(kt);
    STAGE_SK(kt);
    __syncthreads();
    BODYB;
  }

  // ---------------- epilogue ----------------
  float z = (z4[0] + z4[1]) + (z4[2] + z4[3]);
  z += __shfl_xor(z, 16);
  z += __shfl_xor(z, 32);
  const float rz = 1.0f / z;
  const float ss = rz / 255.f;

  const size_t rowoff = ((size_t)(b * Ntok + n0 + (wv << 4) + i16)) * DIMC + h * HD_;
  const int sbase = bh * 80;
#pragma unroll
  for (int dg = 0; dg < 5; ++dg) {
    const int d0 = dg * 16 + (h4 << 2);
    if (d0 < HD_) {
      float4 o;
      int t0 = pv[dg][0] + (cs[sbase + d0 + 0] << 7);
      int t1 = pv[dg][1] + (cs[sbase + d0 + 1] << 7);
      int t2 = pv[dg][2] + (cs[sbase + d0 + 2] << 7);
      int t3 = pv[dg][3] + (cs[sbase + d0 + 3] << 7);
      o.x = (float)t0 * sv[sbase + d0 + 0] * ss;
      o.y = (float)t1 * sv[sbase + d0 + 1] * ss;
      o.z = (float)t2 * sv[sbase + d0 + 2] * ss;
      o.w = (float)t3 * sv[sbase + d0 + 3] * ss;
      if (SPLIT) {
        ushort4 hh, mm, ll;
        split1(o.x, hh.x, mm.x, ll.x);
        split1(o.y, hh.y, mm.y, ll.y);
        split1(o.z, hh.z, mm.z, ll.z);
        split1(o.w, hh.w, mm.w, ll.w);
        *(ushort4*)(ah + rowoff + d0) = hh;
        *(ushort4*)(am + rowoff + d0) = mm;
        *(ushort4*)(al + rowoff + d0) = ll;
      } else {
        *(float4*)(aoutF + rowoff + d0) = o;
      }
    }
  }
}

// ---------------------------------------------------------------------------
// New-path workspace layout (aliased):
constexpr size_t SZ_QKV  = (size_t)Mrows * C3 * 4;        // 56,623,104
constexpr size_t PL_X    = (size_t)Mrows * DIMC * 2;      //  9,437,184 (x/a plane)
constexpr size_t PL_WQ   = (size_t)C3 * DIMC * 2;         //  7,962,624
constexpr size_t PL_WP   = (size_t)DIMC * DIMC * 2;       //  2,654,208
constexpr size_t OFF_XA  = SZ_QKV;                        // x-planes, later a-planes
constexpr size_t OFF_WQ  = OFF_XA + 3 * PL_X;             // wq-planes, later int8 bufs
constexpr size_t OFF_WP  = OFF_WQ + 3 * PL_WQ;
constexpr size_t REQ_NEW = OFF_WP + 3 * PL_WP;            // 116,785,152
// int8/scale aliases inside WQ region (WQ dead after qkv-gemm):
constexpr size_t SZ_Q8 = (size_t)Bz * H * Ntok * 128;     // 8,388,608
constexpr size_t SZ_V8 = (size_t)Bz * H * 80 * 2048;      // 5,242,880
constexpr size_t SZ_S  = (size_t)Bz * H * Ntok * 4;       //   524,288
constexpr size_t SZ_SV = (size_t)Bz * H * 80 * 4;         //    10,240
constexpr size_t A_Q8 = OFF_WQ;
constexpr size_t A_K8 = A_Q8 + SZ_Q8;
constexpr size_t A_V8 = A_K8 + SZ_Q8;
constexpr size_t A_SQ = A_V8 + SZ_V8;
constexpr size_t A_SK = A_SQ + SZ_S;
constexpr size_t A_SV = A_SK + SZ_S;
constexpr size_t A_CS = A_SV + SZ_SV;
static_assert(A_CS + SZ_SV <= OFF_WP, "alias overflow");
// Fallback (round-3) layout:
constexpr size_t F_AOUT = SZ_QKV;
constexpr size_t F_Q8   = F_AOUT + (size_t)Mrows * DIMC * 4;
constexpr size_t F_K8   = F_Q8 + SZ_Q8;
constexpr size_t F_V8   = F_K8 + SZ_Q8;
constexpr size_t F_SQ   = F_V8 + SZ_V8;
constexpr size_t F_SK   = F_SQ + SZ_S;
constexpr size_t F_SV   = F_SK + SZ_S;
constexpr size_t F_CS   = F_SV + SZ_SV;

extern "C" void kernel_launch(void* const* d_in, const int* in_sizes, int n_in,
                              void* d_out, int out_size, void* d_ws, size_t ws_size,
                              hipStream_t stream) {
  const float* x      = (const float*)d_in[0];
  const float* w_qkv  = (const float*)d_in[1];
  const float* w_proj = (const float*)d_in[2];
  const float* b_proj = (const float*)d_in[3];
  float* out = (float*)d_out;
  char* ws = (char*)d_ws;
  float* qkv = (float*)ws;

  if (ws_size >= REQ_NEW) {
    unsigned short* xh = (unsigned short*)(ws + OFF_XA);
    unsigned short* xm = xh + PL_X / 2;
    unsigned short* xl = xm + PL_X / 2;
    unsigned short* wqh = (unsigned short*)(ws + OFF_WQ);
    unsigned short* wqm = wqh + PL_WQ / 2;
    unsigned short* wql = wqm + PL_WQ / 2;
    unsigned short* wph = (unsigned short*)(ws + OFF_WP);
    unsigned short* wpm = wph + PL_WP / 2;
    unsigned short* wpl = wpm + PL_WP / 2;
    signed char* q8  = (signed char*)(ws + A_Q8);
    signed char* k8  = (signed char*)(ws + A_K8);
    signed char* vT8 = (signed char*)(ws + A_V8);
    float* sq = (float*)(ws + A_SQ);
    float* sk = (float*)(ws + A_SK);
    float* sv = (float*)(ws + A_SV);
    int*   cs = (int*)(ws + A_CS);
    // a-planes alias x-planes (x dead after qkv-gemm; attn writes them)
    unsigned short* ah = xh;
    unsigned short* am = xm;
    unsigned short* al = xl;

    split3_kernel<<<2048, 256, 0, stream>>>(x, xh, xm, xl, Mrows * DIMC / 4);
    split3_kernel<<<2048, 256, 0, stream>>>(w_qkv, wqh, wqm, wql, C3 * DIMC / 4);
    split3_kernel<<<1297, 256, 0, stream>>>(w_proj, wph, wpm, wpl, DIMC * DIMC / 4);
    gemm3<false><<<dim3(C3 / 128, Mrows / 128), 256, 0, stream>>>(
        xh, xm, xl, wqh, wqm, wql, nullptr, qkv, Mrows, C3, DIMC);
    quant_qk_pack<<<(Bz * Ntok * 2 * H) / 4, 256, 0, stream>>>(qkv, q8, k8, sq, sk);
    quant_v_pack<<<Bz * H * 80, 256, 0, stream>>>(qkv, vT8, sv, cs);
    attn_mfma<true><<<Bz * H * (Ntok / 64), 256, 0, stream>>>(
        q8, k8, vT8, sq, sk, sv, cs, nullptr, ah, am, al);
    gemm3<true><<<dim3(DIMC / 128, Mrows / 128), 256, 0, stream>>>(
        ah, am, al, wph, wpm, wpl, b_proj, out, Mrows, DIMC, DIMC);
  } else {
    // -------- fallback: round-3 fp32-vector-GEMM path --------
    float* aout = (float*)(ws + F_AOUT);
    signed char* q8  = (signed char*)(ws + F_Q8);
    signed char* k8  = (signed char*)(ws + F_K8);
    signed char* vT8 = (signed char*)(ws + F_V8);
    float* sq = (float*)(ws + F_SQ);
    float* sk = (float*)(ws + F_SK);
    float* sv = (float*)(ws + F_SV);
    int*   cs = (int*)(ws + F_CS);
    gemm_bt<false><<<dim3(C3 / 128, Mrows / 128), 256, 0, stream>>>(
        x, w_qkv, nullptr, qkv, Mrows, C3, DIMC);
    quant_qk_pack<<<(Bz * Ntok * 2 * H) / 4, 256, 0, stream>>>(qkv, q8, k8, sq, sk);
    quant_v_pack<<<Bz * H * 80, 256, 0, stream>>>(qkv, vT8, sv, cs);
    attn_mfma<false><<<Bz * H * (Ntok / 64), 256, 0, stream>>>(
        q8, k8, vT8, sq, sk, sv, cs, aout, nullptr, nullptr, nullptr);
    gemm_bt<true><<<dim3(DIMC / 128, Mrows / 128), 256, 0, stream>>>(
        aout, w_proj, b_proj, out, Mrows, DIMC, DIMC);
  }
}

// Round 8
// 495.968 us; speedup vs baseline: 5.0521x; 1.0163x over previous
//
#include <hip/hip_runtime.h>
#include <math.h>

// ---------------------------------------------------------------------------
// QuantizedAttention (round 8): conflict-free plane-packed gemm3 + proj BN=64.
//   gemm3 LDS layout (round-7 was 8-way bank-conflicted, 11.9M conflicts):
//     planes h,m packed side-by-side -> 128-B rows, 3-bit XOR key (row&7)<<4
//       => frag reads 2-way (free). plane l: 64-B rows, 2-bit key => 4-way.
//     Swizzle on GLOBAL source addr (linear global_load_lds dest) + same XOR
//     on ds_read. 
//   gemm3 templated on NF (n-frags/wave): qkv NF=4 (BN=128, 864 blocks),
//     proj NF=2 (BN=64, 576 blocks; round-7 had 288 blocks = tail-bound).
//   attn_mfma / quants / splits / fallback identical to round 7.
// jnp.round == half-even -> rintf. New-path workspace 116.8 MB (aliased).
// ---------------------------------------------------------------------------

typedef int   i32x4  __attribute__((ext_vector_type(4)));
typedef short bf16x8 __attribute__((ext_vector_type(8)));
typedef float f32x4  __attribute__((ext_vector_type(4)));

constexpr int Bz   = 2;
constexpr int Ntok = 2048;
constexpr int DIMC = 1152;
constexpr int H    = 16;
constexpr int HD_  = 72;
constexpr int Mrows = Bz * Ntok;   // 4096
constexpr int C3    = 3 * DIMC;    // 3456

// ---------------- bf16 split helpers ---------------------------------------
__device__ __forceinline__ unsigned short f2bf(float f) {
  unsigned u = __float_as_uint(f);
  return (unsigned short)((u + 0x7fffu + ((u >> 16) & 1u)) >> 16);   // RNE
}
__device__ __forceinline__ float bf2f(unsigned short h) {
  return __uint_as_float((unsigned)h << 16);
}
__device__ __forceinline__ void split1(float v, unsigned short& h,
                                       unsigned short& m, unsigned short& l) {
  h = f2bf(v); float r1 = v - bf2f(h);      // exact
  m = f2bf(r1); float r2 = r1 - bf2f(m);    // exact
  l = f2bf(r2);
}

__global__ __launch_bounds__(256)
void split3_kernel(const float* __restrict__ src, unsigned short* __restrict__ ph,
                   unsigned short* __restrict__ pm, unsigned short* __restrict__ pl,
                   int n4) {
  for (int i = blockIdx.x * 256 + threadIdx.x; i < n4; i += gridDim.x * 256) {
    float4 v = ((const float4*)src)[i];
    ushort4 h, m, l;
    split1(v.x, h.x, m.x, l.x);
    split1(v.y, h.y, m.y, l.y);
    split1(v.z, h.z, m.z, l.z);
    split1(v.w, h.w, m.w, l.w);
    ((ushort4*)ph)[i] = h;
    ((ushort4*)pm)[i] = m;
    ((ushort4*)pl)[i] = l;
  }
}

// ---------------- async global->LDS ----------------------------------------
__device__ __forceinline__ void gload16(const void* g, void* l) {
  __builtin_amdgcn_global_load_lds(
      (const __attribute__((address_space(1))) unsigned int*)g,
      (__attribute__((address_space(3))) unsigned int*)l, 16, 0, 0);
}

// ---------------- bf16x3 MFMA GEMM, plane-packed LDS ------------------------
// C[m][n] = sum_k A(m,k)*W(n,k) (+bias). BM=128, BN=32*NF (per block).
template<bool BIAS, int NF>
__global__ __launch_bounds__(256)
void gemm3(const unsigned short* __restrict__ Ah, const unsigned short* __restrict__ Am,
           const unsigned short* __restrict__ Al,
           const unsigned short* __restrict__ Bh, const unsigned short* __restrict__ Bm,
           const unsigned short* __restrict__ Bl,
           const float* __restrict__ bias, float* __restrict__ C,
           int Md, int Nd, int Kd) {
  constexpr int BN = 32 * NF;
  __shared__ __align__(16) char Apk[128 * 128];   // h|m packed, 128B rows, swz3
  __shared__ __align__(16) char Alt[128 * 64];    // l, 64B rows, swz2
  __shared__ __align__(16) char Bpk[BN * 128];
  __shared__ __align__(16) char Blt[BN * 64];
  const int t = threadIdx.x, lane = t & 63, wv = t >> 6;
  const int r15 = lane & 15, h4 = lane >> 4;
  // XCD-aware bijective block remap (nwg%8==0 for both instantiations)
  const int gx = gridDim.x;
  const int nwg = gx * gridDim.y;
  const int orig = blockIdx.y * gx + blockIdx.x;
  const int qq = nwg >> 3;
  const int wg = (orig & 7) * qq + (orig >> 3);
  const int bm = (wg / gx) << 7, bn = (wg % gx) * BN;
  const int wn = (wv & 1) * (BN / 2), wm = (wv >> 1) << 6;

  f32x4 acc[4][NF];
#pragma unroll
  for (int i = 0; i < 4; ++i)
#pragma unroll
    for (int j = 0; j < NF; ++j) acc[i][j] = (f32x4){0.f, 0.f, 0.f, 0.f};

  const int k3 = (r15 & 7) << 4;      // 3-bit XOR key (packed tiles)
  const int k2 = (r15 & 3) << 4;      // 2-bit XOR key (l tiles)

  for (int k0 = 0; k0 < Kd; k0 += 32) {
    __syncthreads();                  // previous step's compute done
    // ---- stage A packed (h|m): 16KB, swz3 on source col ----
#pragma unroll
    for (int c = 0; c < 4; ++c) {
      const int L = (t + (c << 8)) << 4;
      const int row = L >> 7;
      const int scol = (L & 127) ^ ((row & 7) << 4);
      const unsigned short* sp = (scol & 64) ? Am : Ah;
      gload16((const char*)(sp + (size_t)(bm + row) * Kd + k0) + (scol & 63),
              Apk + L);
    }
    // ---- stage A l: 8KB, swz2 ----
#pragma unroll
    for (int c = 0; c < 2; ++c) {
      const int L = (t + (c << 8)) << 4;
      const int row = L >> 6;
      const int scol = (L & 63) ^ ((row & 3) << 4);
      gload16((const char*)(Al + (size_t)(bm + row) * Kd + k0) + scol, Alt + L);
    }
    // ---- stage B packed: BN*128 B ----
#pragma unroll
    for (int c = 0; c < NF; ++c) {
      const int L = (t + (c << 8)) << 4;
      const int row = L >> 7;
      const int scol = (L & 127) ^ ((row & 7) << 4);
      const unsigned short* sp = (scol & 64) ? Bm : Bh;
      gload16((const char*)(sp + (size_t)(bn + row) * Kd + k0) + (scol & 63),
              Bpk + L);
    }
    // ---- stage B l: BN*64 B ----
#pragma unroll
    for (int c = 0; c < NF / 2; ++c) {
      const int L = (t + (c << 8)) << 4;
      const int row = L >> 6;
      const int scol = (L & 63) ^ ((row & 3) << 4);
      gload16((const char*)(Bl + (size_t)(bn + row) * Kd + k0) + scol, Blt + L);
    }
    __syncthreads();                  // barrier drains vmcnt

    bf16x8 bf[3][NF];
#pragma unroll
    for (int c = 0; c < NF; ++c) {
      const int br = wn + c * 16 + r15;
      bf[0][c] = *(const bf16x8*)(Bpk + br * 128 + ((h4 << 4) ^ k3));
      bf[1][c] = *(const bf16x8*)(Bpk + br * 128 + ((64 | (h4 << 4)) ^ k3));
      bf[2][c] = *(const bf16x8*)(Blt + br * 64 + ((h4 << 4) ^ k2));
    }
#pragma unroll
    for (int pa = 0; pa < 3; ++pa) {
#pragma unroll
      for (int mf = 0; mf < 4; ++mf) {
        const int ar = wm + mf * 16 + r15;
        bf16x8 af;
        if (pa == 0)      af = *(const bf16x8*)(Apk + ar * 128 + ((h4 << 4) ^ k3));
        else if (pa == 1) af = *(const bf16x8*)(Apk + ar * 128 + ((64 | (h4 << 4)) ^ k3));
        else              af = *(const bf16x8*)(Alt + ar * 64 + ((h4 << 4) ^ k2));
#pragma unroll
        for (int bp = 0; bp < 3; ++bp) {
          if (bp < 3 - pa) {          // pairs: h*{h,m,l}, m*{h,m}, l*{h}
#pragma unroll
            for (int nf = 0; nf < NF; ++nf)
              acc[mf][nf] = __builtin_amdgcn_mfma_f32_16x16x32_bf16(
                  bf[bp][nf], af, acc[mf][nf], 0, 0, 0);
          }
        }
      }
    }
  }
  // epilogue: D col(lane&15)=m, row((lane>>4)*4+reg)=n -> float4 along n
#pragma unroll
  for (int mf = 0; mf < 4; ++mf) {
    const int m = bm + wm + mf * 16 + r15;
#pragma unroll
    for (int nf = 0; nf < NF; ++nf) {
      const int n = bn + wn + nf * 16 + (h4 << 2);
      float4 o;
      o.x = acc[mf][nf][0]; o.y = acc[mf][nf][1];
      o.z = acc[mf][nf][2]; o.w = acc[mf][nf][3];
      if (BIAS) {
        o.x += bias[n]; o.y += bias[n + 1]; o.z += bias[n + 2]; o.w += bias[n + 3];
      }
      *(float4*)(C + (size_t)m * Nd + n) = o;
    }
  }
}

// ---------------- fp32 vector GEMM (fallback path only) ---------------------
template<bool BIAS>
__global__ __launch_bounds__(256)
void gemm_bt(const float* __restrict__ A, const float* __restrict__ W,
             const float* __restrict__ bias, float* __restrict__ Cout,
             int Md, int Nd, int Kd) {
  __shared__ float As[16][132];
  __shared__ float Bs[16][132];
  const int t  = threadIdx.x;
  const int bm = blockIdx.y << 7, bn = blockIdx.x << 7;
  const int lr = t >> 1;
  const int lk = (t & 1) << 3;
  const float* Ap = A + (size_t)(bm + lr) * Kd + lk;
  const float* Wp = W + (size_t)(bn + lr) * Kd + lk;
  const int tx = t & 15, ty = t >> 4;
  float acc[8][8] = {};
  for (int k0 = 0; k0 < Kd; k0 += 16) {
    float4 a0 = *(const float4*)(Ap + k0);
    float4 a1 = *(const float4*)(Ap + k0 + 4);
    float4 w0 = *(const float4*)(Wp + k0);
    float4 w1 = *(const float4*)(Wp + k0 + 4);
    __syncthreads();
    As[lk + 0][lr] = a0.x; As[lk + 1][lr] = a0.y;
    As[lk + 2][lr] = a0.z; As[lk + 3][lr] = a0.w;
    As[lk + 4][lr] = a1.x; As[lk + 5][lr] = a1.y;
    As[lk + 6][lr] = a1.z; As[lk + 7][lr] = a1.w;
    Bs[lk + 0][lr] = w0.x; Bs[lk + 1][lr] = w0.y;
    Bs[lk + 2][lr] = w0.z; Bs[lk + 3][lr] = w0.w;
    Bs[lk + 4][lr] = w1.x; Bs[lk + 5][lr] = w1.y;
    Bs[lk + 6][lr] = w1.z; Bs[lk + 7][lr] = w1.w;
    __syncthreads();
#pragma unroll
    for (int kk = 0; kk < 16; ++kk) {
      float4 x0 = *(const float4*)&As[kk][(ty << 3) + 0];
      float4 x1 = *(const float4*)&As[kk][(ty << 3) + 4];
      float4 y0 = *(const float4*)&Bs[kk][(tx << 3) + 0];
      float4 y1 = *(const float4*)&Bs[kk][(tx << 3) + 4];
      float ar[8] = {x0.x, x0.y, x0.z, x0.w, x1.x, x1.y, x1.z, x1.w};
      float br[8] = {y0.x, y0.y, y0.z, y0.w, y1.x, y1.y, y1.z, y1.w};
#pragma unroll
      for (int i = 0; i < 8; ++i)
#pragma unroll
        for (int j = 0; j < 8; ++j)
          acc[i][j] = fmaf(ar[i], br[j], acc[i][j]);
    }
  }
  float bias8[8] = {0.f, 0.f, 0.f, 0.f, 0.f, 0.f, 0.f, 0.f};
  if (BIAS) {
#pragma unroll
    for (int j = 0; j < 8; ++j) bias8[j] = bias[bn + (tx << 3) + j];
  }
#pragma unroll
  for (int i = 0; i < 8; ++i) {
    const int m = bm + (ty << 3) + i;
    float* cp = Cout + (size_t)m * Nd + bn + (tx << 3);
    float4 o0, o1;
    o0.x = acc[i][0] + bias8[0]; o0.y = acc[i][1] + bias8[1];
    o0.z = acc[i][2] + bias8[2]; o0.w = acc[i][3] + bias8[3];
    o1.x = acc[i][4] + bias8[4]; o1.y = acc[i][5] + bias8[5];
    o1.z = acc[i][6] + bias8[6]; o1.w = acc[i][7] + bias8[7];
    *(float4*)(cp + 0) = o0;
    *(float4*)(cp + 4) = o1;
  }
}

// --------- quant q,k -> int8 rows (pad 72->128) + scales -------------------
__global__ __launch_bounds__(256)
void quant_qk_pack(const float* __restrict__ qkv,
                   signed char* __restrict__ q8, signed char* __restrict__ k8,
                   float* __restrict__ sq, float* __restrict__ sk) {
  const int wid  = (blockIdx.x << 2) + (threadIdx.x >> 6);  // one wave per row
  const int lane = threadIdx.x & 63;
  const int h  = wid & 15;
  const int g  = (wid >> 4) & 1;        // 0=q, 1=k
  const int bn = wid >> 5;              // 0..4095 = b*2048+n
  const float* row = qkv + (size_t)bn * C3 + g * DIMC + h * HD_;
  float x0 = row[lane];
  float x1 = (lane < 8) ? row[64 + lane] : 0.f;
  float amax = fmaxf(fabsf(x0), fabsf(x1));
#pragma unroll
  for (int s = 32; s; s >>= 1) amax = fmaxf(amax, __shfl_xor(amax, s));
  const float scale = fmaxf(amax, 1e-8f) / 127.f;
  int q0 = (int)fminf(fmaxf(rintf(x0 / scale), -128.f), 127.f);
  int q1 = (int)fminf(fmaxf(rintf(x1 / scale), -128.f), 127.f);
  const int b = bn >> 11, n = bn & 2047;
  signed char* dst = (g ? k8 : q8) + ((size_t)(b * H + h) * Ntok + n) * 128;
  dst[lane] = (signed char)q0;
  dst[64 + lane] = (lane < 8) ? (signed char)q1 : 0;   // zero-pad 72..127
  if (lane == 0) (g ? sk : sq)[(size_t)(b * H + h) * Ntok + n] = scale;
}

// --------- quant v -> int8 transposed [B,H,80,2048] + scale + colsum -------
__global__ __launch_bounds__(256)
void quant_v_pack(const float* __restrict__ qkv, signed char* __restrict__ vT8,
                  float* __restrict__ sv, int* __restrict__ cs) {
  const int col = blockIdx.x;           // 0..2559
  const int d = col % 80;
  const int h = (col / 80) % H;
  const int b = col / (80 * H);
  const int idx = (b * H + h) * 80 + d;
  signed char* vrow = vT8 + (size_t)idx * 2048;
  const int t = threadIdx.x;
  if (d >= HD_) {                       // zero pad rows 72..79
#pragma unroll
    for (int i = 0; i < 8; ++i) vrow[t + (i << 8)] = 0;
    if (t == 0) { sv[idx] = 0.f; cs[idx] = 0; }
    return;
  }
  const float* base = qkv + (size_t)b * Ntok * C3 + 2 * DIMC + h * HD_ + d;
  float vals[8];
  float amax = 0.f;
#pragma unroll
  for (int i = 0; i < 8; ++i) {
    float v = base[(size_t)(t + (i << 8)) * C3];
    vals[i] = v;
    amax = fmaxf(amax, fabsf(v));
  }
#pragma unroll
  for (int s = 32; s; s >>= 1) amax = fmaxf(amax, __shfl_xor(amax, s));
  __shared__ float red[4];
  if ((t & 63) == 0) red[t >> 6] = amax;
  __syncthreads();
  amax = fmaxf(fmaxf(red[0], red[1]), fmaxf(red[2], red[3]));
  const float scale = fmaxf(amax, 1e-8f) / 127.f;
  int isum = 0;
#pragma unroll
  for (int i = 0; i < 8; ++i) {
    int q = (int)fminf(fmaxf(rintf(vals[i] / scale), -128.f), 127.f);
    vrow[t + (i << 8)] = (signed char)q;
    isum += q;
  }
#pragma unroll
  for (int s = 32; s; s >>= 1) isum += __shfl_xor(isum, s);
  __shared__ int ired[4];
  if ((t & 63) == 0) ired[t >> 6] = isum;
  __syncthreads();
  if (t == 0) {
    cs[idx] = ired[0] + ired[1] + ired[2] + ired[3];
    sv[idx] = scale;
  }
}

// --------- int8-MFMA fused attention, LDS-staged ---------------------------
__device__ __forceinline__ float logitv(float cl, float skj, int a) {
  return cl * skj * (float)a;   // exact cvt (|a|<2^24); identical in both passes
}

#define STAGE_K(KT)                                                          \
  {                                                                          \
    _Pragma("unroll")                                                        \
    for (int c_ = 0; c_ < 2; ++c_) {                                         \
      const int L_ = (t + (c_ << 8)) << 4;                                   \
      const int row_ = L_ >> 7;                                              \
      const int col_ = L_ & 127;                                             \
      gload16(kgbase + (size_t)(KT) * 8192 + row_ * 128 +                    \
                  (col_ ^ ((row_ & 7) << 4)),                                \
              Ks + L_);                                                      \
    }                                                                        \
  }
#define STAGE_SK(KT)                                                         \
  if (t < 16) {                                                              \
    gload16(skgbase + (KT) * 256 + (t << 4), (signed char*)Sks + (t << 4));  \
  }
#define STAGE_V(KT)                                                          \
  {                                                                          \
    const int L_ = t << 4;                                                   \
    const int row_ = L_ >> 6, col_ = L_ & 63;                                \
    gload16(vgbase + (size_t)row_ * 2048 + (KT) * 64 +                       \
                (col_ ^ ((row_ & 3) << 4)),                                  \
            Vs + L_);                                                        \
    if (t < 64) {                                                            \
      const int L2_ = (t + 256) << 4;                                        \
      const int row2_ = L2_ >> 6, col2_ = L2_ & 63;                          \
      gload16(vgbase + (size_t)row2_ * 2048 + (KT) * 64 +                    \
                  (col2_ ^ ((row2_ & 3) << 4)),                              \
              Vs + L2_);                                                     \
    }                                                                        \
  }

#define BODYA                                                                 \
  {                                                                           \
    _Pragma("unroll")                                                         \
    for (int g_ = 0; g_ < 4; ++g_) {                                          \
      const int krow_ = (g_ << 4) + i16;                                      \
      const int kx_ = (krow_ & 7) << 4;                                       \
      const i32x4 kf0_ = *(const i32x4*)&Ks[krow_ * 128 + ((h4 << 4) ^ kx_)]; \
      const i32x4 kf1_ = *(const i32x4*)&Ks[krow_ * 128 + ((64 | (h4 << 4)) ^ kx_)]; \
      i32x4 acc_ = {0, 0, 0, 0};                                              \
      acc_ = __builtin_amdgcn_mfma_i32_16x16x64_i8(kf0_, qf0, acc_, 0, 0, 0); \
      acc_ = __builtin_amdgcn_mfma_i32_16x16x64_i8(kf1_, qf1, acc_, 0, 0, 0); \
      const float4 skv_ = *(const float4*)&Sks[(g_ << 4) + (h4 << 2)];        \
      mr4[g_] = fmaxf(mr4[g_], logitv(cl, skv_.x, acc_[0]));                  \
      mr4[g_] = fmaxf(mr4[g_], logitv(cl, skv_.y, acc_[1]));                  \
      mr4[g_] = fmaxf(mr4[g_], logitv(cl, skv_.z, acc_[2]));                  \
      mr4[g_] = fmaxf(mr4[g_], logitv(cl, skv_.w, acc_[3]));                  \
    }                                                                         \
  }

#define BODYB                                                                 \
  {                                                                           \
    _Pragma("unroll")                                                         \
    for (int g_ = 0; g_ < 4; ++g_) {                                          \
      const int krow_ = (g_ << 4) + i16;                                      \
      const int kx_ = (krow_ & 7) << 4;                                       \
      const i32x4 kf0_ = *(const i32x4*)&Ks[krow_ * 128 + ((h4 << 4) ^ kx_)]; \
      const i32x4 kf1_ = *(const i32x4*)&Ks[krow_ * 128 + ((64 | (h4 << 4)) ^ kx_)]; \
      i32x4 acc_ = {0, 0, 0, 0};                                              \
      acc_ = __builtin_amdgcn_mfma_i32_16x16x64_i8(kf0_, qf0, acc_, 0, 0, 0); \
      acc_ = __builtin_amdgcn_mfma_i32_16x16x64_i8(kf1_, qf1, acc_, 0, 0, 0); \
      const float4 skv_ = *(const float4*)&Sks[(g_ << 4) + (h4 << 2)];        \
      const float sks_[4] = {skv_.x, skv_.y, skv_.z, skv_.w};                 \
      int packed_ = 0;                                                        \
      _Pragma("unroll")                                                       \
      for (int r_ = 0; r_ < 4; ++r_) {                                        \
        const float lv_ = logitv(cl, sks_[r_], acc_[r_]);                     \
        const float e_ = __expf(lv_ - mrow);   /* lv<=mrow bitwise */         \
        z4[g_] += e_;                                                         \
        const float u_ = fminf(rintf(e_ * 255.f), 255.f);                     \
        const int s8_ = (int)u_ - 128;                                        \
        packed_ |= (s8_ & 255) << (r_ << 3);                                  \
      }                                                                       \
      *(int*)&P[wv][(i16 << 6) + ((g_ ^ sI) << 4) + (h4 << 2)] = packed_;     \
    }                                                                         \
    const i32x4 pf_ = *(const i32x4*)&P[wv][(i16 << 6) + ((h4 ^ sI) << 4)];   \
    _Pragma("unroll")                                                         \
    for (int dg_ = 0; dg_ < 5; ++dg_) {                                       \
      const int vrow_ = (dg_ << 4) + i16;                                     \
      const int vx_ = (vrow_ & 3) << 4;                                       \
      const i32x4 vf_ = *(const i32x4*)&Vs[vrow_ * 64 + ((h4 << 4) ^ vx_)];   \
      pv[dg_] = __builtin_amdgcn_mfma_i32_16x16x64_i8(vf_, pf_, pv[dg_], 0, 0, 0); \
    }                                                                         \
  }

template<bool SPLIT>
__global__ __launch_bounds__(256)
void attn_mfma(const signed char* __restrict__ q8, const signed char* __restrict__ k8,
               const signed char* __restrict__ vT8,
               const float* __restrict__ sq, const float* __restrict__ sk,
               const float* __restrict__ sv, const int* __restrict__ cs,
               float* __restrict__ aoutF,
               unsigned short* __restrict__ ah, unsigned short* __restrict__ am,
               unsigned short* __restrict__ al) {
  const int bid = ((blockIdx.x & 7) << 7) + (blockIdx.x >> 3);
  const int qt = bid & 31, h = (bid >> 5) & 15, b = bid >> 9;
  const int n0 = qt << 6;
  const int t = threadIdx.x, lane = t & 63, wv = t >> 6;
  const int i16 = lane & 15, h4 = lane >> 4;
  const int bh = b * H + h;
  const int sI = (i16 >> 1) & 3;

  __shared__ __align__(16) signed char Ks[8192];    // 64 keys x 128 B (swz)
  __shared__ __align__(16) signed char Vs[5120];    // 80 d x 64 B (swz)
  __shared__ __align__(16) float Sks[64];
  __shared__ __align__(16) signed char P[4][1024];

  const int qrow = n0 + (wv << 4) + i16;
  const signed char* qp = q8 + ((size_t)bh * Ntok + qrow) * 128 + (h4 << 4);
  const i32x4 qf0 = *(const i32x4*)qp;
  const i32x4 qf1 = *(const i32x4*)(qp + 64);
  const float cl = sq[(size_t)bh * Ntok + qrow] * 0.11785113019775793f;
  const signed char* kgbase  = k8 + (size_t)bh * Ntok * 128;
  const signed char* vgbase  = vT8 + (size_t)bh * 80 * 2048;
  const signed char* skgbase = (const signed char*)(sk + (size_t)bh * Ntok);

  float mr4[4];
#pragma unroll
  for (int g = 0; g < 4; ++g) mr4[g] = -3.4e38f;
  for (int kt = 0; kt < 32; ++kt) {
    __syncthreads();
    STAGE_K(kt);
    STAGE_SK(kt);
    __syncthreads();
    BODYA;
  }
  float mrow = fmaxf(fmaxf(mr4[0], mr4[1]), fmaxf(mr4[2], mr4[3]));
  mrow = fmaxf(mrow, __shfl_xor(mrow, 16));
  mrow = fmaxf(mrow, __shfl_xor(mrow, 32));

  float z4[4] = {0.f, 0.f, 0.f, 0.f};
  i32x4 pv[5];
#pragma unroll
  for (int dg = 0; dg < 5; ++dg) pv[dg] = (i32x4){0, 0, 0, 0};

  for (int kt = 0; kt < 32; ++kt) {
    __syncthreads();
    STAGE_K(kt);
    STAGE_V(kt);
    STAGE_SK(kt);
    __syncthreads();
    BODYB;
  }

  float z = (z4[0] + z4[1]) + (z4[2] + z4[3]);
  z += __shfl_xor(z, 16);
  z += __shfl_xor(z, 32);
  const float rz = 1.0f / z;
  const float ss = rz / 255.f;

  const size_t rowoff = ((size_t)(b * Ntok + n0 + (wv << 4) + i16)) * DIMC + h * HD_;
  const int sbase = bh * 80;
#pragma unroll
  for (int dg = 0; dg < 5; ++dg) {
    const int d0 = dg * 16 + (h4 << 2);
    if (d0 < HD_) {
      float4 o;
      int t0 = pv[dg][0] + (cs[sbase + d0 + 0] << 7);
      int t1 = pv[dg][1] + (cs[sbase + d0 + 1] << 7);
      int t2 = pv[dg][2] + (cs[sbase + d0 + 2] << 7);
      int t3 = pv[dg][3] + (cs[sbase + d0 + 3] << 7);
      o.x = (float)t0 * sv[sbase + d0 + 0] * ss;
      o.y = (float)t1 * sv[sbase + d0 + 1] * ss;
      o.z = (float)t2 * sv[sbase + d0 + 2] * ss;
      o.w = (float)t3 * sv[sbase + d0 + 3] * ss;
      if (SPLIT) {
        ushort4 hh, mm, ll;
        split1(o.x, hh.x, mm.x, ll.x);
        split1(o.y, hh.y, mm.y, ll.y);
        split1(o.z, hh.z, mm.z, ll.z);
        split1(o.w, hh.w, mm.w, ll.w);
        *(ushort4*)(ah + rowoff + d0) = hh;
        *(ushort4*)(am + rowoff + d0) = mm;
        *(ushort4*)(al + rowoff + d0) = ll;
      } else {
        *(float4*)(aoutF + rowoff + d0) = o;
      }
    }
  }
}

// ---------------------------------------------------------------------------
// New-path workspace layout (aliased):
constexpr size_t SZ_QKV  = (size_t)Mrows * C3 * 4;        // 56,623,104
constexpr size_t PL_X    = (size_t)Mrows * DIMC * 2;      //  9,437,184 (x/a plane)
constexpr size_t PL_WQ   = (size_t)C3 * DIMC * 2;         //  7,962,624
constexpr size_t PL_WP   = (size_t)DIMC * DIMC * 2;       //  2,654,208
constexpr size_t OFF_XA  = SZ_QKV;                        // x-planes, later a-planes
constexpr size_t OFF_WQ  = OFF_XA + 3 * PL_X;             // wq-planes, later int8 bufs
constexpr size_t OFF_WP  = OFF_WQ + 3 * PL_WQ;
constexpr size_t REQ_NEW = OFF_WP + 3 * PL_WP;            // 116,785,152
// int8/scale aliases inside WQ region (WQ dead after qkv-gemm):
constexpr size_t SZ_Q8 = (size_t)Bz * H * Ntok * 128;     // 8,388,608
constexpr size_t SZ_V8 = (size_t)Bz * H * 80 * 2048;      // 5,242,880
constexpr size_t SZ_S  = (size_t)Bz * H * Ntok * 4;       //   524,288
constexpr size_t SZ_SV = (size_t)Bz * H * 80 * 4;         //    10,240
constexpr size_t A_Q8 = OFF_WQ;
constexpr size_t A_K8 = A_Q8 + SZ_Q8;
constexpr size_t A_V8 = A_K8 + SZ_Q8;
constexpr size_t A_SQ = A_V8 + SZ_V8;
constexpr size_t A_SK = A_SQ + SZ_S;
constexpr size_t A_SV = A_SK + SZ_S;
constexpr size_t A_CS = A_SV + SZ_SV;
static_assert(A_CS + SZ_SV <= OFF_WP, "alias overflow");
// Fallback (round-3) layout:
constexpr size_t F_AOUT = SZ_QKV;
constexpr size_t F_Q8   = F_AOUT + (size_t)Mrows * DIMC * 4;
constexpr size_t F_K8   = F_Q8 + SZ_Q8;
constexpr size_t F_V8   = F_K8 + SZ_Q8;
constexpr size_t F_SQ   = F_V8 + SZ_V8;
constexpr size_t F_SK   = F_SQ + SZ_S;
constexpr size_t F_SV   = F_SK + SZ_S;
constexpr size_t F_CS   = F_SV + SZ_SV;

extern "C" void kernel_launch(void* const* d_in, const int* in_sizes, int n_in,
                              void* d_out, int out_size, void* d_ws, size_t ws_size,
                              hipStream_t stream) {
  const float* x      = (const float*)d_in[0];
  const float* w_qkv  = (const float*)d_in[1];
  const float* w_proj = (const float*)d_in[2];
  const float* b_proj = (const float*)d_in[3];
  float* out = (float*)d_out;
  char* ws = (char*)d_ws;
  float* qkv = (float*)ws;

  if (ws_size >= REQ_NEW) {
    unsigned short* xh = (unsigned short*)(ws + OFF_XA);
    unsigned short* xm = xh + PL_X / 2;
    unsigned short* xl = xm + PL_X / 2;
    unsigned short* wqh = (unsigned short*)(ws + OFF_WQ);
    unsigned short* wqm = wqh + PL_WQ / 2;
    unsigned short* wql = wqm + PL_WQ / 2;
    unsigned short* wph = (unsigned short*)(ws + OFF_WP);
    unsigned short* wpm = wph + PL_WP / 2;
    unsigned short* wpl = wpm + PL_WP / 2;
    signed char* q8  = (signed char*)(ws + A_Q8);
    signed char* k8  = (signed char*)(ws + A_K8);
    signed char* vT8 = (signed char*)(ws + A_V8);
    float* sq = (float*)(ws + A_SQ);
    float* sk = (float*)(ws + A_SK);
    float* sv = (float*)(ws + A_SV);
    int*   cs = (int*)(ws + A_CS);
    unsigned short* ah = xh;
    unsigned short* am = xm;
    unsigned short* al = xl;

    split3_kernel<<<2048, 256, 0, stream>>>(x, xh, xm, xl, Mrows * DIMC / 4);
    split3_kernel<<<2048, 256, 0, stream>>>(w_qkv, wqh, wqm, wql, C3 * DIMC / 4);
    split3_kernel<<<1297, 256, 0, stream>>>(w_proj, wph, wpm, wpl, DIMC * DIMC / 4);
    gemm3<false, 4><<<dim3(C3 / 128, Mrows / 128), 256, 0, stream>>>(
        xh, xm, xl, wqh, wqm, wql, nullptr, qkv, Mrows, C3, DIMC);
    quant_qk_pack<<<(Bz * Ntok * 2 * H) / 4, 256, 0, stream>>>(qkv, q8, k8, sq, sk);
    quant_v_pack<<<Bz * H * 80, 256, 0, stream>>>(qkv, vT8, sv, cs);
    attn_mfma<true><<<Bz * H * (Ntok / 64), 256, 0, stream>>>(
        q8, k8, vT8, sq, sk, sv, cs, nullptr, ah, am, al);
    gemm3<true, 2><<<dim3(DIMC / 64, Mrows / 128), 256, 0, stream>>>(
        ah, am, al, wph, wpm, wpl, b_proj, out, Mrows, DIMC, DIMC);
  } else {
    // -------- fallback: round-3 fp32-vector-GEMM path --------
    float* aout = (float*)(ws + F_AOUT);
    signed char* q8  = (signed char*)(ws + F_Q8);
    signed char* k8  = (signed char*)(ws + F_K8);
    signed char* vT8 = (signed char*)(ws + F_V8);
    float* sq = (float*)(ws + F_SQ);
    float* sk = (float*)(ws + F_SK);
    float* sv = (float*)(ws + F_SV);
    int*   cs = (int*)(ws + F_CS);
    gemm_bt<false><<<dim3(C3 / 128, Mrows / 128), 256, 0, stream>>>(
        x, w_qkv, nullptr, qkv, Mrows, C3, DIMC);
    quant_qk_pack<<<(Bz * Ntok * 2 * H) / 4, 256, 0, stream>>>(qkv, q8, k8, sq, sk);
    quant_v_pack<<<Bz * H * 80, 256, 0, stream>>>(qkv, vT8, sv, cs);
    attn_mfma<false><<<Bz * H * (Ntok / 64), 256, 0, stream>>>(
        q8, k8, vT8, sq, sk, sv, cs, aout, nullptr, nullptr, nullptr);
    gemm_bt<true><<<dim3(DIMC / 128, Mrows / 128), 256, 0, stream>>>(
        aout, w_proj, b_proj, out, Mrows, DIMC, DIMC);
  }
}